// Round 1
// baseline (1375.861 us; speedup 1.0000x reference)
//
#include <hip/hip_runtime.h>

#define NCLS  80
#define TOPK  1000
#define NLVL  3
#define NIMG  8
#define NCAND 3000
#define NWORD 47            // ceil(3000/64)
#define DETS  100
#define CAP   4096
#define HBINS 8192
#define HBASE 0x3E000       // (bits>>12) of 0.2f region start
#define IMGSZ 2048.0f

// ---------------- helpers ----------------

__device__ __forceinline__ float sigm(float x) {
    if (x >= 0.f) return 1.f / (1.f + expf(-x));
    float e = expf(x);
    return e / (1.f + e);
}

// descending bitonic sort of N u64 keys in LDS (N power of 2, N >= blockDim)
__device__ __forceinline__ void bitonic_desc(unsigned long long* s, int N) {
    for (int k = 2; k <= N; k <<= 1) {
        for (int j = k >> 1; j > 0; j >>= 1) {
            __syncthreads();
            for (int i = threadIdx.x; i < N; i += blockDim.x) {
                int ixj = i ^ j;
                if (ixj > i) {
                    unsigned long long a = s[i], b = s[ixj];
                    bool up = ((i & k) == 0);
                    if (up ? (a < b) : (a > b)) { s[i] = b; s[ixj] = a; }
                }
            }
        }
    }
    __syncthreads();
}

__device__ __forceinline__ unsigned long long shfl_u64(unsigned long long v, int lane) {
    int lo = (int)(unsigned int)v;
    int hi = (int)(unsigned int)(v >> 32);
    lo = __shfl(lo, lane, 64);
    hi = __shfl(hi, lane, 64);
    return ((unsigned long long)(unsigned int)hi << 32) | (unsigned int)lo;
}

__device__ __forceinline__ void lvl_select(int level,
    const float* c0, const float* c1, const float* c2,
    const float* t0, const float* t1, const float* t2,
    const float** cls, const float** ctr, int* hw) {
    if (level == 0)      { *cls = c0; *ctr = t0; *hw = 4096; }
    else if (level == 1) { *cls = c1; *ctr = t1; *hw = 1024; }
    else                 { *cls = c2; *ctr = t2; *hw = 256; }
}

// ---------------- stage 1: histogram of score bits ----------------

__global__ void k_hist(const float* c0, const float* c1, const float* c2,
                       const float* t0, const float* t1, const float* t2,
                       unsigned int* hist) {
    int level = blockIdx.z, img = blockIdx.y;
    const float* cls; const float* ctr; int hw;
    lvl_select(level, c0, c1, c2, t0, t1, t2, &cls, &ctr, &hw);
    int n = hw * NCLS;
    const float* cl = cls + (size_t)img * n;
    const float* ct = ctr + (size_t)img * hw;
    __shared__ unsigned int h[HBINS];
    for (int i = threadIdx.x; i < HBINS; i += blockDim.x) h[i] = 0;
    __syncthreads();
    for (int e = blockIdx.x * blockDim.x + threadIdx.x; e < n; e += gridDim.x * blockDim.x) {
        int a = e / NCLS;
        float s = sqrtf(sigm(cl[e]) * sigm(ct[a]));
        if (s > 0.2f) {
            int bin = (int)(__float_as_uint(s) >> 12) - HBASE;
            bin = min(max(bin, 0), HBINS - 1);
            atomicAdd(&h[bin], 1u);
        }
    }
    __syncthreads();
    unsigned int* gh = hist + (size_t)(img * NLVL + level) * HBINS;
    for (int i = threadIdx.x; i < HBINS; i += blockDim.x)
        if (h[i]) atomicAdd(&gh[i], h[i]);
}

// ---------------- stage 2: find cutoff bits V per (img,level) ----------------

__global__ void k_find(const unsigned int* hist, unsigned int* vcut) {
    int pair = blockIdx.x;
    __shared__ unsigned int hv[HBINS];
    for (int i = threadIdx.x; i < HBINS; i += blockDim.x)
        hv[i] = hist[(size_t)pair * HBINS + i];
    __syncthreads();
    if (threadIdx.x == 0) {
        unsigned int cum = 0, V = 0;
        for (int i = HBINS - 1; i >= 0; --i) {
            unsigned int c = hv[i];
            if (cum + c >= (unsigned int)TOPK) { V = ((unsigned int)(i + HBASE)) << 12; break; }
            cum += c;
        }
        vcut[pair] = V;   // V==0 => collect all passing (only if <1000 pass)
    }
}

// ---------------- stage 3: collect candidates with bits >= V ----------------

__global__ void k_collect(const float* c0, const float* c1, const float* c2,
                          const float* t0, const float* t1, const float* t2,
                          const unsigned int* vcut, unsigned int* counters,
                          unsigned long long* buf) {
    int level = blockIdx.z, img = blockIdx.y;
    const float* cls; const float* ctr; int hw;
    lvl_select(level, c0, c1, c2, t0, t1, t2, &cls, &ctr, &hw);
    int n = hw * NCLS;
    int pair = img * NLVL + level;
    const float* cl = cls + (size_t)img * n;
    const float* ct = ctr + (size_t)img * hw;
    unsigned int V = vcut[pair];
    for (int e = blockIdx.x * blockDim.x + threadIdx.x; e < n; e += gridDim.x * blockDim.x) {
        int a = e / NCLS;
        float s = sqrtf(sigm(cl[e]) * sigm(ct[a]));
        if (s > 0.2f) {
            unsigned int bits = __float_as_uint(s);
            if (bits >= V) {
                unsigned int slot = atomicAdd(&counters[pair], 1u);
                if (slot < CAP)
                    buf[(size_t)pair * CAP + slot] =
                        ((unsigned long long)bits << 32) | (unsigned int)(~(unsigned int)e);
            }
        }
    }
}

// ---------------- stage 4: per-(img,level) sort -> top-1000, decode boxes ----------------

__global__ void __launch_bounds__(1024)
k_sort_pairs(const unsigned long long* buf, const unsigned int* counters,
             const float* r0, const float* r1, const float* r2,
             const float* a0, const float* a1, const float* a2,
             float* cand_box, int* cand_lab, unsigned long long* gkey) {
    int pair = blockIdx.x;
    int img = pair / NLVL, level = pair % NLVL;
    __shared__ unsigned long long s[CAP];
    int cnt = (int)counters[pair]; if (cnt > CAP) cnt = CAP;
    for (int i = threadIdx.x; i < CAP; i += blockDim.x)
        s[i] = (i < cnt) ? buf[(size_t)pair * CAP + i] : 0ull;
    bitonic_desc(s, CAP);   // leading __syncthreads inside covers the load
    const float* reg; const float* anc; int hw;
    if (level == 0)      { reg = r0; anc = a0; hw = 4096; }
    else if (level == 1) { reg = r1; anc = a1; hw = 1024; }
    else                 { reg = r2; anc = a2; hw = 256; }
    const float* rg = reg + (size_t)img * hw * 4;
    for (int r = threadIdx.x; r < TOPK; r += blockDim.x) {
        unsigned long long key = s[r];
        int cpos = level * TOPK + r;
        size_t o = (size_t)img * NCAND + cpos;
        float b0 = 0, b1 = 0, b2 = 0, b3 = 0; int lab = 0; unsigned int bits = 0;
        if (key != 0ull) {
            bits = (unsigned int)(key >> 32);
            unsigned int idx = ~((unsigned int)key);
            int a = (int)(idx / NCLS); lab = (int)(idx % NCLS);
            float ax1 = anc[a * 4 + 0], ay1 = anc[a * 4 + 1];
            float ax2 = anc[a * 4 + 2], ay2 = anc[a * 4 + 3];
            float cx = 0.5f * (ax1 + ax2), cy = 0.5f * (ay1 + ay2);
            float w = ax2 - ax1, h = ay2 - ay1;
            float e0 = rg[a * 4 + 0] * w, e1 = rg[a * 4 + 1] * h;
            float e2 = rg[a * 4 + 2] * w, e3 = rg[a * 4 + 3] * h;
            b0 = fminf(fmaxf(cx - e0, 0.f), IMGSZ);
            b1 = fminf(fmaxf(cy - e1, 0.f), IMGSZ);
            b2 = fminf(fmaxf(cx + e2, 0.f), IMGSZ);
            b3 = fminf(fmaxf(cy + e3, 0.f), IMGSZ);
        }
        cand_box[o * 4 + 0] = b0; cand_box[o * 4 + 1] = b1;
        cand_box[o * 4 + 2] = b2; cand_box[o * 4 + 3] = b3;
        cand_lab[o] = lab;
        gkey[o] = ((unsigned long long)bits << 32) | (unsigned int)(~((unsigned int)cpos));
    }
}

// ---------------- stage 5: per-image global sort of 3000, gather + offset boxes ----------------

__global__ void __launch_bounds__(1024)
k_global_sort(const unsigned long long* gkey, const float* cand_box, const int* cand_lab,
              float* ss, float* sbox, int* slab, float* bs) {
    int img = blockIdx.x;
    __shared__ unsigned long long s[4096];
    for (int i = threadIdx.x; i < 4096; i += blockDim.x)
        s[i] = (i < NCAND) ? gkey[(size_t)img * NCAND + i] : 0ull;
    bitonic_desc(s, 4096);
    for (int r = threadIdx.x; r < NCAND; r += blockDim.x) {
        unsigned long long key = s[r];
        unsigned int pos = ~((unsigned int)key);
        float val = __uint_as_float((unsigned int)(key >> 32));
        size_t src = (size_t)img * NCAND + pos;
        size_t dst = (size_t)img * NCAND + r;
        ss[dst] = val;
        int lab = cand_lab[src];
        slab[dst] = lab;
        float off = (float)lab * (IMGSZ + 1.0f);
        float b0 = cand_box[src * 4 + 0], b1 = cand_box[src * 4 + 1];
        float b2 = cand_box[src * 4 + 2], b3 = cand_box[src * 4 + 3];
        sbox[dst * 4 + 0] = b0; sbox[dst * 4 + 1] = b1;
        sbox[dst * 4 + 2] = b2; sbox[dst * 4 + 3] = b3;
        bs[dst * 4 + 0] = b0 + off; bs[dst * 4 + 1] = b1 + off;
        bs[dst * 4 + 2] = b2 + off; bs[dst * 4 + 3] = b3 + off;
    }
}

// ---------------- stage 6: IoU suppression mask (64x64 tiles) ----------------

__global__ void k_nms_mask(const float* bs, unsigned long long* mask) {
    int img = blockIdx.z;
    int i = blockIdx.y * 64 + threadIdx.x;
    int j0 = blockIdx.x * 64;
    __shared__ float4 cb[64];
    const float* B = bs + (size_t)img * NCAND * 4;
    int j = j0 + threadIdx.x;
    if (j < NCAND)
        cb[threadIdx.x] = make_float4(B[j * 4 + 0], B[j * 4 + 1], B[j * 4 + 2], B[j * 4 + 3]);
    __syncthreads();
    if (i >= NCAND) return;
    float x1 = B[i * 4 + 0], y1 = B[i * 4 + 1], x2 = B[i * 4 + 2], y2 = B[i * 4 + 3];
    float ai = (x2 - x1) * (y2 - y1);
    unsigned long long w64 = 0ull;
    int jmax = min(64, NCAND - j0);
    for (int jj = 0; jj < jmax; ++jj) {
        int jg = j0 + jj;
        if (jg > i) {
            float4 c = cb[jj];
            float aj = (c.z - c.x) * (c.w - c.y);
            float lx = fmaxf(x1, c.x), ly = fmaxf(y1, c.y);
            float rx = fminf(x2, c.z), ry = fminf(y2, c.w);
            float w = fmaxf(rx - lx, 0.f), h = fmaxf(ry - ly, 0.f);
            float inter = w * h;
            float iou = inter / (ai + aj - inter);
            if (iou > 0.6f) w64 |= (1ull << jj);
        }
    }
    mask[((size_t)img * NCAND + i) * NWORD + blockIdx.x] = w64;
}

// ---------------- stage 7: serial greedy resolve + fsc ----------------

__global__ void k_nms_serial(const unsigned long long* mask, const float* ss, float* fsc) {
    int img = blockIdx.x;
    __shared__ unsigned long long rows[64 * NWORD];
    const unsigned long long* M = mask + (size_t)img * NCAND * NWORD;
    unsigned long long rem = 0ull;   // lane t holds suppressed-word t (t < NWORD)
    for (int c0 = 0; c0 < NCAND; c0 += 64) {
        int nrows = min(64, NCAND - c0);
        for (int t = threadIdx.x; t < nrows * NWORD; t += 64)
            rows[t] = M[(size_t)c0 * NWORD + t];
        __syncthreads();
        for (int k = 0; k < nrows; ++k) {
            int i = c0 + k;
            unsigned long long w = shfl_u64(rem, i >> 6);
            bool kept = !((w >> (i & 63)) & 1ull);
            if (kept && threadIdx.x < NWORD)
                rem |= rows[k * NWORD + threadIdx.x];
        }
        __syncthreads();
    }
    for (int r = threadIdx.x; r < NCAND; r += 64) {
        unsigned long long w = shfl_u64(rem, r >> 6);
        bool kept = !((w >> (r & 63)) & 1ull);
        float v = ss[(size_t)img * NCAND + r];
        fsc[(size_t)img * NCAND + r] = (kept && v > 0.f) ? v : -1.0f;
    }
}

// ---------------- stage 8: final top-100 + output ----------------

__global__ void __launch_bounds__(1024)
k_final(const float* fsc, const float* sbox, const int* slab, float* out) {
    int img = blockIdx.x;
    __shared__ unsigned long long s[4096];
    for (int i = threadIdx.x; i < 4096; i += blockDim.x) {
        unsigned long long key = 0ull;
        if (i < NCAND) {
            unsigned int u = __float_as_uint(fsc[(size_t)img * NCAND + i]);
            unsigned int k32 = (u & 0x80000000u) ? ~u : (u | 0x80000000u);
            key = ((unsigned long long)k32 << 32) | (unsigned int)(~(unsigned int)i);
        }
        s[i] = key;
    }
    bitonic_desc(s, 4096);
    for (int k = threadIdx.x; k < DETS; k += blockDim.x) {
        unsigned long long key = s[k];
        unsigned int r = ~((unsigned int)key);
        unsigned int k32 = (unsigned int)(key >> 32);
        unsigned int u = (k32 & 0x80000000u) ? (k32 & 0x7FFFFFFFu) : ~k32;
        float score = __uint_as_float(u);
        size_t src = (size_t)img * NCAND + r;
        // boxes [8,100,4] then scores [8,100] then labels [8,100], all float32
        out[((size_t)img * DETS + k) * 4 + 0] = sbox[src * 4 + 0];
        out[((size_t)img * DETS + k) * 4 + 1] = sbox[src * 4 + 1];
        out[((size_t)img * DETS + k) * 4 + 2] = sbox[src * 4 + 2];
        out[((size_t)img * DETS + k) * 4 + 3] = sbox[src * 4 + 3];
        out[NIMG * DETS * 4 + img * DETS + k] = score;
        out[NIMG * DETS * 5 + img * DETS + k] = (float)slab[src];
    }
}

// ---------------- launch ----------------

extern "C" void kernel_launch(void* const* d_in, const int* in_sizes, int n_in,
                              void* d_out, int out_size, void* d_ws, size_t ws_size,
                              hipStream_t stream) {
    (void)in_sizes; (void)n_in; (void)out_size; (void)ws_size;
    // setup_inputs() dict order: cls0, reg0, ctr0, anc0, cls1, reg1, ctr1, anc1, cls2, reg2, ctr2, anc2
    const float* cls0 = (const float*)d_in[0];
    const float* reg0 = (const float*)d_in[1];
    const float* ctr0 = (const float*)d_in[2];
    const float* anc0 = (const float*)d_in[3];
    const float* cls1 = (const float*)d_in[4];
    const float* reg1 = (const float*)d_in[5];
    const float* ctr1 = (const float*)d_in[6];
    const float* anc1 = (const float*)d_in[7];
    const float* cls2 = (const float*)d_in[8];
    const float* reg2 = (const float*)d_in[9];
    const float* ctr2 = (const float*)d_in[10];
    const float* anc2 = (const float*)d_in[11];
    float* out = (float*)d_out;
    char* ws = (char*)d_ws;

    // workspace layout (bytes)
    const size_t OFF_HIST = 0;                 // 24*8192*4   = 786432
    const size_t OFF_CNT  = 786432;            // 24*4
    const size_t OFF_VCUT = 786560;            // 24*4
    const size_t ZERO_B   = 786688;            // hist + counters (+vcut, harmless)
    const size_t OFF_BUF  = 786688;            // 24*4096*8   = 786432
    const size_t OFF_CBOX = 1573120;           // 8*3000*4*4  = 384000
    const size_t OFF_CLAB = 1957120;           // 8*3000*4    = 96000
    const size_t OFF_GKEY = 2053120;           // 8*3000*8    = 192000
    const size_t OFF_SS   = 2245120;           // 96000
    const size_t OFF_SBOX = 2341120;           // 384000
    const size_t OFF_SLAB = 2725120;           // 96000
    const size_t OFF_BS   = 2821120;           // 384000
    const size_t OFF_FSC  = 3205120;           // 96000
    const size_t OFF_MASK = 3301120;           // 8*3000*47*8 = 9024000 -> total 12325120

    unsigned int* hist = (unsigned int*)(ws + OFF_HIST);
    unsigned int* cnt  = (unsigned int*)(ws + OFF_CNT);
    unsigned int* vcut = (unsigned int*)(ws + OFF_VCUT);
    unsigned long long* buf  = (unsigned long long*)(ws + OFF_BUF);
    float* cand_box = (float*)(ws + OFF_CBOX);
    int*   cand_lab = (int*)(ws + OFF_CLAB);
    unsigned long long* gkey = (unsigned long long*)(ws + OFF_GKEY);
    float* ss   = (float*)(ws + OFF_SS);
    float* sbox = (float*)(ws + OFF_SBOX);
    int*   slab = (int*)(ws + OFF_SLAB);
    float* bs   = (float*)(ws + OFF_BS);
    float* fsc  = (float*)(ws + OFF_FSC);
    unsigned long long* mask = (unsigned long long*)(ws + OFF_MASK);

    hipMemsetAsync(ws, 0, ZERO_B, stream);

    dim3 tgrid(64, NIMG, NLVL);
    k_hist<<<tgrid, 256, 0, stream>>>(cls0, cls1, cls2, ctr0, ctr1, ctr2, hist);
    k_find<<<24, 256, 0, stream>>>(hist, vcut);
    k_collect<<<tgrid, 256, 0, stream>>>(cls0, cls1, cls2, ctr0, ctr1, ctr2, vcut, cnt, buf);
    k_sort_pairs<<<24, 1024, 0, stream>>>(buf, cnt, reg0, reg1, reg2, anc0, anc1, anc2,
                                          cand_box, cand_lab, gkey);
    k_global_sort<<<NIMG, 1024, 0, stream>>>(gkey, cand_box, cand_lab, ss, sbox, slab, bs);
    k_nms_mask<<<dim3(NWORD, NWORD, NIMG), 64, 0, stream>>>(bs, mask);
    k_nms_serial<<<NIMG, 64, 0, stream>>>(mask, ss, fsc);
    k_final<<<NIMG, 1024, 0, stream>>>(fsc, sbox, slab, out);
}

// Round 2
// 725.412 us; speedup vs baseline: 1.8967x; 1.8967x over previous
//
#include <hip/hip_runtime.h>

#define NCLS  80
#define TOPK  1000
#define NLVL  3
#define NIMG  8
#define NCAND 3000
#define NWORD 47            // ceil(3000/64) == number of 64-bit chunks
#define DETS  100
#define CAP   4096
#define HBINS 8192
#define HBASE 0x3E000       // (bits>>12) of 0.2f region start
#define IMGSZ 2048.0f

// ---------------- helpers ----------------

__device__ __forceinline__ float sigm(float x) {
    if (x >= 0.f) return 1.f / (1.f + expf(-x));
    float e = expf(x);
    return e / (1.f + e);
}

// descending bitonic sort of N u64 keys in LDS (N power of 2, N >= blockDim)
__device__ __forceinline__ void bitonic_desc(unsigned long long* s, int N) {
    for (int k = 2; k <= N; k <<= 1) {
        for (int j = k >> 1; j > 0; j >>= 1) {
            __syncthreads();
            for (int i = threadIdx.x; i < N; i += blockDim.x) {
                int ixj = i ^ j;
                if (ixj > i) {
                    unsigned long long a = s[i], b = s[ixj];
                    bool up = ((i & k) == 0);
                    if (up ? (a < b) : (a > b)) { s[i] = b; s[ixj] = a; }
                }
            }
        }
    }
    __syncthreads();
}

__device__ __forceinline__ unsigned long long shfl_u64(unsigned long long v, int lane) {
    int lo = (int)(unsigned int)v;
    int hi = (int)(unsigned int)(v >> 32);
    lo = __shfl(lo, lane, 64);
    hi = __shfl(hi, lane, 64);
    return ((unsigned long long)(unsigned int)hi << 32) | (unsigned int)lo;
}

__device__ __forceinline__ void lvl_select(int level,
    const float* c0, const float* c1, const float* c2,
    const float* t0, const float* t1, const float* t2,
    const float** cls, const float** ctr, int* hw) {
    if (level == 0)      { *cls = c0; *ctr = t0; *hw = 4096; }
    else if (level == 1) { *cls = c1; *ctr = t1; *hw = 1024; }
    else                 { *cls = c2; *ctr = t2; *hw = 256; }
}

// ---------------- stage 1: histogram of score bits ----------------

__global__ void k_hist(const float* c0, const float* c1, const float* c2,
                       const float* t0, const float* t1, const float* t2,
                       unsigned int* hist) {
    int level = blockIdx.z, img = blockIdx.y;
    const float* cls; const float* ctr; int hw;
    lvl_select(level, c0, c1, c2, t0, t1, t2, &cls, &ctr, &hw);
    int n = hw * NCLS;
    const float* cl = cls + (size_t)img * n;
    const float* ct = ctr + (size_t)img * hw;
    __shared__ unsigned int h[HBINS];
    for (int i = threadIdx.x; i < HBINS; i += blockDim.x) h[i] = 0;
    __syncthreads();
    for (int e = blockIdx.x * blockDim.x + threadIdx.x; e < n; e += gridDim.x * blockDim.x) {
        int a = e / NCLS;
        float s = sqrtf(sigm(cl[e]) * sigm(ct[a]));
        if (s > 0.2f) {
            int bin = (int)(__float_as_uint(s) >> 12) - HBASE;
            bin = min(max(bin, 0), HBINS - 1);
            atomicAdd(&h[bin], 1u);
        }
    }
    __syncthreads();
    unsigned int* gh = hist + (size_t)(img * NLVL + level) * HBINS;
    for (int i = threadIdx.x; i < HBINS; i += blockDim.x)
        if (h[i]) atomicAdd(&gh[i], h[i]);
}

// ---------------- stage 2: find cutoff bits V per (img,level) ----------------

__global__ void k_find(const unsigned int* hist, unsigned int* vcut) {
    int pair = blockIdx.x;
    __shared__ unsigned int hv[HBINS];
    for (int i = threadIdx.x; i < HBINS; i += blockDim.x)
        hv[i] = hist[(size_t)pair * HBINS + i];
    __syncthreads();
    if (threadIdx.x == 0) {
        unsigned int cum = 0, V = 0;
        for (int i = HBINS - 1; i >= 0; --i) {
            unsigned int c = hv[i];
            if (cum + c >= (unsigned int)TOPK) { V = ((unsigned int)(i + HBASE)) << 12; break; }
            cum += c;
        }
        vcut[pair] = V;   // V==0 => collect all passing (only if <1000 pass)
    }
}

// ---------------- stage 3: collect candidates with bits >= V ----------------

__global__ void k_collect(const float* c0, const float* c1, const float* c2,
                          const float* t0, const float* t1, const float* t2,
                          const unsigned int* vcut, unsigned int* counters,
                          unsigned long long* buf) {
    int level = blockIdx.z, img = blockIdx.y;
    const float* cls; const float* ctr; int hw;
    lvl_select(level, c0, c1, c2, t0, t1, t2, &cls, &ctr, &hw);
    int n = hw * NCLS;
    int pair = img * NLVL + level;
    const float* cl = cls + (size_t)img * n;
    const float* ct = ctr + (size_t)img * hw;
    unsigned int V = vcut[pair];
    for (int e = blockIdx.x * blockDim.x + threadIdx.x; e < n; e += gridDim.x * blockDim.x) {
        int a = e / NCLS;
        float s = sqrtf(sigm(cl[e]) * sigm(ct[a]));
        if (s > 0.2f) {
            unsigned int bits = __float_as_uint(s);
            if (bits >= V) {
                unsigned int slot = atomicAdd(&counters[pair], 1u);
                if (slot < CAP)
                    buf[(size_t)pair * CAP + slot] =
                        ((unsigned long long)bits << 32) | (unsigned int)(~(unsigned int)e);
            }
        }
    }
}

// ---------------- stage 4: per-(img,level) sort -> top-1000, decode boxes ----------------

__global__ void __launch_bounds__(1024)
k_sort_pairs(const unsigned long long* buf, const unsigned int* counters,
             const float* r0, const float* r1, const float* r2,
             const float* a0, const float* a1, const float* a2,
             float* cand_box, int* cand_lab, unsigned long long* gkey) {
    int pair = blockIdx.x;
    int img = pair / NLVL, level = pair % NLVL;
    __shared__ unsigned long long s[CAP];
    int cnt = (int)counters[pair]; if (cnt > CAP) cnt = CAP;
    for (int i = threadIdx.x; i < CAP; i += blockDim.x)
        s[i] = (i < cnt) ? buf[(size_t)pair * CAP + i] : 0ull;
    bitonic_desc(s, CAP);   // leading __syncthreads inside covers the load
    const float* reg; const float* anc; int hw;
    if (level == 0)      { reg = r0; anc = a0; hw = 4096; }
    else if (level == 1) { reg = r1; anc = a1; hw = 1024; }
    else                 { reg = r2; anc = a2; hw = 256; }
    const float* rg = reg + (size_t)img * hw * 4;
    for (int r = threadIdx.x; r < TOPK; r += blockDim.x) {
        unsigned long long key = s[r];
        int cpos = level * TOPK + r;
        size_t o = (size_t)img * NCAND + cpos;
        float b0 = 0, b1 = 0, b2 = 0, b3 = 0; int lab = 0; unsigned int bits = 0;
        if (key != 0ull) {
            bits = (unsigned int)(key >> 32);
            unsigned int idx = ~((unsigned int)key);
            int a = (int)(idx / NCLS); lab = (int)(idx % NCLS);
            float ax1 = anc[a * 4 + 0], ay1 = anc[a * 4 + 1];
            float ax2 = anc[a * 4 + 2], ay2 = anc[a * 4 + 3];
            float cx = 0.5f * (ax1 + ax2), cy = 0.5f * (ay1 + ay2);
            float w = ax2 - ax1, h = ay2 - ay1;
            float e0 = rg[a * 4 + 0] * w, e1 = rg[a * 4 + 1] * h;
            float e2 = rg[a * 4 + 2] * w, e3 = rg[a * 4 + 3] * h;
            b0 = fminf(fmaxf(cx - e0, 0.f), IMGSZ);
            b1 = fminf(fmaxf(cy - e1, 0.f), IMGSZ);
            b2 = fminf(fmaxf(cx + e2, 0.f), IMGSZ);
            b3 = fminf(fmaxf(cy + e3, 0.f), IMGSZ);
        }
        cand_box[o * 4 + 0] = b0; cand_box[o * 4 + 1] = b1;
        cand_box[o * 4 + 2] = b2; cand_box[o * 4 + 3] = b3;
        cand_lab[o] = lab;
        gkey[o] = ((unsigned long long)bits << 32) | (unsigned int)(~((unsigned int)cpos));
    }
}

// ---------------- stage 5: per-image global sort of 3000, gather + offset boxes ----------------

__global__ void __launch_bounds__(1024)
k_global_sort(const unsigned long long* gkey, const float* cand_box, const int* cand_lab,
              float* ss, float* sbox, int* slab, float* bs) {
    int img = blockIdx.x;
    __shared__ unsigned long long s[4096];
    for (int i = threadIdx.x; i < 4096; i += blockDim.x)
        s[i] = (i < NCAND) ? gkey[(size_t)img * NCAND + i] : 0ull;
    bitonic_desc(s, 4096);
    for (int r = threadIdx.x; r < NCAND; r += blockDim.x) {
        unsigned long long key = s[r];
        unsigned int pos = ~((unsigned int)key);
        float val = __uint_as_float((unsigned int)(key >> 32));
        size_t src = (size_t)img * NCAND + pos;
        size_t dst = (size_t)img * NCAND + r;
        ss[dst] = val;
        int lab = cand_lab[src];
        slab[dst] = lab;
        float off = (float)lab * (IMGSZ + 1.0f);
        float b0 = cand_box[src * 4 + 0], b1 = cand_box[src * 4 + 1];
        float b2 = cand_box[src * 4 + 2], b3 = cand_box[src * 4 + 3];
        sbox[dst * 4 + 0] = b0; sbox[dst * 4 + 1] = b1;
        sbox[dst * 4 + 2] = b2; sbox[dst * 4 + 3] = b3;
        bs[dst * 4 + 0] = b0 + off; bs[dst * 4 + 1] = b1 + off;
        bs[dst * 4 + 2] = b2 + off; bs[dst * 4 + 3] = b3 + off;
    }
}

// ---------------- stage 6: IoU suppression mask (64x64 tiles) ----------------

__global__ void k_nms_mask(const float* bs, unsigned long long* mask) {
    int img = blockIdx.z;
    int i = blockIdx.y * 64 + threadIdx.x;
    int j0 = blockIdx.x * 64;
    __shared__ float4 cb[64];
    const float* B = bs + (size_t)img * NCAND * 4;
    int j = j0 + threadIdx.x;
    if (j < NCAND)
        cb[threadIdx.x] = make_float4(B[j * 4 + 0], B[j * 4 + 1], B[j * 4 + 2], B[j * 4 + 3]);
    __syncthreads();
    if (i >= NCAND) return;
    float x1 = B[i * 4 + 0], y1 = B[i * 4 + 1], x2 = B[i * 4 + 2], y2 = B[i * 4 + 3];
    float ai = (x2 - x1) * (y2 - y1);
    unsigned long long w64 = 0ull;
    int jmax = min(64, NCAND - j0);
    for (int jj = 0; jj < jmax; ++jj) {
        int jg = j0 + jj;
        if (jg > i) {
            float4 c = cb[jj];
            float aj = (c.z - c.x) * (c.w - c.y);
            float lx = fmaxf(x1, c.x), ly = fmaxf(y1, c.y);
            float rx = fminf(x2, c.z), ry = fminf(y2, c.w);
            float w = fmaxf(rx - lx, 0.f), h = fmaxf(ry - ly, 0.f);
            float inter = w * h;
            float iou = inter / (ai + aj - inter);
            if (iou > 0.6f) w64 |= (1ull << jj);
        }
    }
    mask[((size_t)img * NCAND + i) * NWORD + blockIdx.x] = w64;
}

// ---------------- stage 7: serial greedy resolve (single-wave, async prefetch) ----------------

// Issue an async global->LDS copy of `bytes` (multiple of 16) from gsrc_base
// to lds_base. Single wave: lane t covers bytes [i*1024 + 16t, +16).
__device__ __forceinline__ void async_copy_chunk(const unsigned long long* gsrc_base,
                                                 unsigned long long* lds_base,
                                                 int bytes, int t) {
    const char* g = (const char*)gsrc_base + t * 16;
    char* l = (char*)lds_base;
    int nfull = bytes >> 10;
    for (int i = 0; i < nfull; ++i)
        __builtin_amdgcn_global_load_lds(
            (__attribute__((address_space(1))) void*)(g + i * 1024),
            (__attribute__((address_space(3))) void*)(l + i * 1024), 16, 0, 0);
    int remb = bytes & 1023;
    if (remb && t * 16 < remb)
        __builtin_amdgcn_global_load_lds(
            (__attribute__((address_space(1))) void*)(g + nfull * 1024),
            (__attribute__((address_space(3))) void*)(l + nfull * 1024), 16, 0, 0);
}

// Resolve one 64-column chunk: compute kept bits (all lanes redundantly, scalar
// chain ~4 VALU/bit), then OR kept rows' words into per-lane rem.
#define PROCESS_CHUNK(BUF, CIDX) do {                                          \
    int _c = (CIDX);                                                           \
    int _nr = NCAND - _c * 64; if (_nr > 64) _nr = 64;                         \
    unsigned long long _selfw = (t < _nr) ? BUF[t * NWORD + _c] : 0ull;        \
    sw[t] = _selfw;                                                            \
    unsigned long long _cur = shfl_u64(rem, _c);                               \
    unsigned long long _kept = 0ull;                                           \
    for (int _g = 0; _g < 64; _g += 8) {                                       \
        unsigned long long _s0 = sw[_g + 0], _s1 = sw[_g + 1],                 \
                           _s2 = sw[_g + 2], _s3 = sw[_g + 3],                 \
                           _s4 = sw[_g + 4], _s5 = sw[_g + 5],                 \
                           _s6 = sw[_g + 6], _s7 = sw[_g + 7];                 \
        if (!((_cur >> (_g + 0)) & 1ull)) { _kept |= 1ull << (_g + 0); _cur |= _s0; } \
        if (!((_cur >> (_g + 1)) & 1ull)) { _kept |= 1ull << (_g + 1); _cur |= _s1; } \
        if (!((_cur >> (_g + 2)) & 1ull)) { _kept |= 1ull << (_g + 2); _cur |= _s2; } \
        if (!((_cur >> (_g + 3)) & 1ull)) { _kept |= 1ull << (_g + 3); _cur |= _s3; } \
        if (!((_cur >> (_g + 4)) & 1ull)) { _kept |= 1ull << (_g + 4); _cur |= _s4; } \
        if (!((_cur >> (_g + 5)) & 1ull)) { _kept |= 1ull << (_g + 5); _cur |= _s5; } \
        if (!((_cur >> (_g + 6)) & 1ull)) { _kept |= 1ull << (_g + 6); _cur |= _s6; } \
        if (!((_cur >> (_g + 7)) & 1ull)) { _kept |= 1ull << (_g + 7); _cur |= _s7; } \
    }                                                                          \
    if (_nr < 64) _kept &= ((1ull << _nr) - 1ull);                             \
    if (t == 0) keptm[_c] = _kept;                                             \
    if (t < NWORD) {                                                           \
        unsigned long long _acc = 0ull;                                        \
        _Pragma("unroll 8")                                                    \
        for (int _k = 0; _k < 64; ++_k)                                        \
            _acc |= BUF[_k * NWORD + t] &                                      \
                    (unsigned long long)(-(long long)((_kept >> _k) & 1ull));  \
        rem |= _acc;                                                           \
    }                                                                          \
} while (0)

__global__ void __launch_bounds__(64)
k_nms_serial(const unsigned long long* mask, const float* ss, float* fsc) {
    int img = blockIdx.x;
    int t = threadIdx.x;
    // one wave per block: no __syncthreads anywhere (wave-lockstep + in-order LDS),
    // so the async LDS-DMA prefetch is never drained by a barrier's vmcnt(0).
    __shared__ unsigned long long bufA[64 * NWORD];
    __shared__ unsigned long long bufB[64 * NWORD];
    __shared__ unsigned long long sw[64];
    __shared__ unsigned long long keptm[NWORD];
    const unsigned long long* M = mask + (size_t)img * NCAND * NWORD;
    unsigned long long rem = 0ull;   // lane t holds suppressed-word t (t < NWORD)

    async_copy_chunk(M, bufA, 64 * NWORD * 8, t);
    __builtin_amdgcn_s_waitcnt(0x0F70);    // vmcnt(0) only

    for (int c = 0; c < 46; c += 2) {
        {   // prefetch chunk c+1 into bufB while resolving chunk c from bufA
            int nr = NCAND - (c + 1) * 64; if (nr > 64) nr = 64;
            async_copy_chunk(M + (size_t)(c + 1) * 64 * NWORD, bufB, nr * NWORD * 8, t);
        }
        PROCESS_CHUNK(bufA, c);
        __builtin_amdgcn_s_waitcnt(0x0F70);
        if (c + 2 < NWORD) {   // prefetch chunk c+2 into bufA while resolving c+1
            int nr = NCAND - (c + 2) * 64; if (nr > 64) nr = 64;
            async_copy_chunk(M + (size_t)(c + 2) * 64 * NWORD, bufA, nr * NWORD * 8, t);
        }
        PROCESS_CHUNK(bufB, c + 1);
        __builtin_amdgcn_s_waitcnt(0x0F70);
    }
    PROCESS_CHUNK(bufA, 46);   // last chunk (56 rows), loaded during c==44 iteration

    for (int r = t; r < NCAND; r += 64) {
        unsigned long long kw = keptm[r >> 6];   // uniform address per iteration
        bool kept = (kw >> (r & 63)) & 1ull;
        float v = ss[(size_t)img * NCAND + r];
        fsc[(size_t)img * NCAND + r] = (kept && v > 0.f) ? v : -1.0f;
    }
}

// ---------------- stage 8: final top-100 + output ----------------

__global__ void __launch_bounds__(1024)
k_final(const float* fsc, const float* sbox, const int* slab, float* out) {
    int img = blockIdx.x;
    __shared__ unsigned long long s[4096];
    for (int i = threadIdx.x; i < 4096; i += blockDim.x) {
        unsigned long long key = 0ull;
        if (i < NCAND) {
            unsigned int u = __float_as_uint(fsc[(size_t)img * NCAND + i]);
            unsigned int k32 = (u & 0x80000000u) ? ~u : (u | 0x80000000u);
            key = ((unsigned long long)k32 << 32) | (unsigned int)(~(unsigned int)i);
        }
        s[i] = key;
    }
    bitonic_desc(s, 4096);
    for (int k = threadIdx.x; k < DETS; k += blockDim.x) {
        unsigned long long key = s[k];
        unsigned int r = ~((unsigned int)key);
        unsigned int k32 = (unsigned int)(key >> 32);
        unsigned int u = (k32 & 0x80000000u) ? (k32 & 0x7FFFFFFFu) : ~k32;
        float score = __uint_as_float(u);
        size_t src = (size_t)img * NCAND + r;
        // boxes [8,100,4] then scores [8,100] then labels [8,100], all float32
        out[((size_t)img * DETS + k) * 4 + 0] = sbox[src * 4 + 0];
        out[((size_t)img * DETS + k) * 4 + 1] = sbox[src * 4 + 1];
        out[((size_t)img * DETS + k) * 4 + 2] = sbox[src * 4 + 2];
        out[((size_t)img * DETS + k) * 4 + 3] = sbox[src * 4 + 3];
        out[NIMG * DETS * 4 + img * DETS + k] = score;
        out[NIMG * DETS * 5 + img * DETS + k] = (float)slab[src];
    }
}

// ---------------- launch ----------------

extern "C" void kernel_launch(void* const* d_in, const int* in_sizes, int n_in,
                              void* d_out, int out_size, void* d_ws, size_t ws_size,
                              hipStream_t stream) {
    (void)in_sizes; (void)n_in; (void)out_size; (void)ws_size;
    // setup_inputs() dict order: cls0, reg0, ctr0, anc0, cls1, reg1, ctr1, anc1, cls2, reg2, ctr2, anc2
    const float* cls0 = (const float*)d_in[0];
    const float* reg0 = (const float*)d_in[1];
    const float* ctr0 = (const float*)d_in[2];
    const float* anc0 = (const float*)d_in[3];
    const float* cls1 = (const float*)d_in[4];
    const float* reg1 = (const float*)d_in[5];
    const float* ctr1 = (const float*)d_in[6];
    const float* anc1 = (const float*)d_in[7];
    const float* cls2 = (const float*)d_in[8];
    const float* reg2 = (const float*)d_in[9];
    const float* ctr2 = (const float*)d_in[10];
    const float* anc2 = (const float*)d_in[11];
    float* out = (float*)d_out;
    char* ws = (char*)d_ws;

    // workspace layout (bytes)
    const size_t OFF_HIST = 0;                 // 24*8192*4   = 786432
    const size_t OFF_CNT  = 786432;            // 24*4
    const size_t OFF_VCUT = 786560;            // 24*4
    const size_t ZERO_B   = 786688;            // hist + counters (+vcut, harmless)
    const size_t OFF_BUF  = 786688;            // 24*4096*8   = 786432
    const size_t OFF_CBOX = 1573120;           // 8*3000*4*4  = 384000
    const size_t OFF_CLAB = 1957120;           // 8*3000*4    = 96000
    const size_t OFF_GKEY = 2053120;           // 8*3000*8    = 192000
    const size_t OFF_SS   = 2245120;           // 96000
    const size_t OFF_SBOX = 2341120;           // 384000
    const size_t OFF_SLAB = 2725120;           // 96000
    const size_t OFF_BS   = 2821120;           // 384000
    const size_t OFF_FSC  = 3205120;           // 96000
    const size_t OFF_MASK = 3301120;           // 8*3000*47*8 = 9024000 -> total 12325120

    unsigned int* hist = (unsigned int*)(ws + OFF_HIST);
    unsigned int* cnt  = (unsigned int*)(ws + OFF_CNT);
    unsigned int* vcut = (unsigned int*)(ws + OFF_VCUT);
    unsigned long long* buf  = (unsigned long long*)(ws + OFF_BUF);
    float* cand_box = (float*)(ws + OFF_CBOX);
    int*   cand_lab = (int*)(ws + OFF_CLAB);
    unsigned long long* gkey = (unsigned long long*)(ws + OFF_GKEY);
    float* ss   = (float*)(ws + OFF_SS);
    float* sbox = (float*)(ws + OFF_SBOX);
    int*   slab = (int*)(ws + OFF_SLAB);
    float* bs   = (float*)(ws + OFF_BS);
    float* fsc  = (float*)(ws + OFF_FSC);
    unsigned long long* mask = (unsigned long long*)(ws + OFF_MASK);

    hipMemsetAsync(ws, 0, ZERO_B, stream);

    dim3 tgrid(64, NIMG, NLVL);
    k_hist<<<tgrid, 256, 0, stream>>>(cls0, cls1, cls2, ctr0, ctr1, ctr2, hist);
    k_find<<<24, 256, 0, stream>>>(hist, vcut);
    k_collect<<<tgrid, 256, 0, stream>>>(cls0, cls1, cls2, ctr0, ctr1, ctr2, vcut, cnt, buf);
    k_sort_pairs<<<24, 1024, 0, stream>>>(buf, cnt, reg0, reg1, reg2, anc0, anc1, anc2,
                                          cand_box, cand_lab, gkey);
    k_global_sort<<<NIMG, 1024, 0, stream>>>(gkey, cand_box, cand_lab, ss, sbox, slab, bs);
    k_nms_mask<<<dim3(NWORD, NWORD, NIMG), 64, 0, stream>>>(bs, mask);
    k_nms_serial<<<NIMG, 64, 0, stream>>>(mask, ss, fsc);
    k_final<<<NIMG, 1024, 0, stream>>>(fsc, sbox, slab, out);
}

// Round 3
// 285.341 us; speedup vs baseline: 4.8218x; 2.5423x over previous
//
#include <hip/hip_runtime.h>

#define NCLS  80
#define TOPK  1000
#define NLVL  3
#define NIMG  8
#define NCAND 3000
#define DETS  100
#define CAP   2048          // cutoff-bin overshoot ~100 expected; 2048 = huge margin
#define HBINS 8192
#define HBASE 0x3E000       // (bits>>12) of 0.125f region start; covers (0.2,1.0]
#define IMGSZ 2048.0f

// ---------------- helpers ----------------

__device__ __forceinline__ float sigm(float x) {
    if (x >= 0.f) return 1.f / (1.f + expf(-x));
    float e = expf(x);
    return e / (1.f + e);
}

// descending bitonic sort of N u64 keys in LDS (N power of 2, N >= blockDim)
__device__ __forceinline__ void bitonic_desc(unsigned long long* s, int N) {
    for (int k = 2; k <= N; k <<= 1) {
        for (int j = k >> 1; j > 0; j >>= 1) {
            __syncthreads();
            for (int i = threadIdx.x; i < N; i += blockDim.x) {
                int ixj = i ^ j;
                if (ixj > i) {
                    unsigned long long a = s[i], b = s[ixj];
                    bool up = ((i & k) == 0);
                    if (up ? (a < b) : (a > b)) { s[i] = b; s[ixj] = a; }
                }
            }
        }
    }
    __syncthreads();
}

__device__ __forceinline__ void lvl_select(int level,
    const float* c0, const float* c1, const float* c2,
    const float* t0, const float* t1, const float* t2,
    const float** cls, const float** ctr, int* hw) {
    if (level == 0)      { *cls = c0; *ctr = t0; *hw = 4096; }
    else if (level == 1) { *cls = c1; *ctr = t1; *hw = 1024; }
    else                 { *cls = c2; *ctr = t2; *hw = 256; }
}

// ---------------- stage 1: histogram of score bits ----------------

__global__ void k_hist(const float* c0, const float* c1, const float* c2,
                       const float* t0, const float* t1, const float* t2,
                       unsigned int* hist) {
    int level = blockIdx.z, img = blockIdx.y;
    const float* cls; const float* ctr; int hw;
    lvl_select(level, c0, c1, c2, t0, t1, t2, &cls, &ctr, &hw);
    int n = hw * NCLS;
    const float* cl = cls + (size_t)img * n;
    const float* ct = ctr + (size_t)img * hw;
    __shared__ unsigned int h[HBINS];
    for (int i = threadIdx.x; i < HBINS; i += blockDim.x) h[i] = 0;
    __syncthreads();
    for (int e = blockIdx.x * blockDim.x + threadIdx.x; e < n; e += gridDim.x * blockDim.x) {
        int a = e / NCLS;
        float s = sqrtf(sigm(cl[e]) * sigm(ct[a]));
        if (s > 0.2f) {
            int bin = (int)(__float_as_uint(s) >> 12) - HBASE;
            bin = min(max(bin, 0), HBINS - 1);
            atomicAdd(&h[bin], 1u);
        }
    }
    __syncthreads();
    unsigned int* gh = hist + (size_t)(img * NLVL + level) * HBINS;
    for (int i = threadIdx.x; i < HBINS; i += blockDim.x)
        if (h[i]) atomicAdd(&gh[i], h[i]);
}

// ---------------- stage 2: find cutoff bits V per (img,level), parallel ----------------

__global__ void k_find(const unsigned int* hist, unsigned int* vcut) {
    int pair = blockIdx.x;
    int tid = threadIdx.x;      // 256 threads; thread tid covers 32 bins, descending
    __shared__ unsigned int segsum[256];
    __shared__ unsigned int pref[256];
    const unsigned int* H = hist + (size_t)pair * HBINS;
    int hi = HBINS - 32 * tid;  // exclusive
    int lo = hi - 32;
    unsigned int s = 0;
    for (int b = lo; b < hi; ++b) s += H[b];
    segsum[tid] = s;
    pref[tid] = s;
    __syncthreads();
    for (int off = 1; off < 256; off <<= 1) {
        unsigned int v = (tid >= off) ? pref[tid - off] : 0u;
        __syncthreads();
        pref[tid] += v;
        __syncthreads();
    }
    unsigned int incl = pref[tid];
    unsigned int excl = incl - segsum[tid];    // count of bins above this segment
    if (excl < (unsigned int)TOPK && incl >= (unsigned int)TOPK) {
        unsigned int cum = excl, V = 0;
        for (int b = hi - 1; b >= lo; --b) {
            unsigned int c = H[b];
            if (cum + c >= (unsigned int)TOPK) { V = ((unsigned int)(b + HBASE)) << 12; break; }
            cum += c;
        }
        vcut[pair] = V;
    }
    if (tid == 255 && pref[255] < (unsigned int)TOPK)
        vcut[pair] = 0;   // fewer than TOPK pass threshold: collect all
}

// ---------------- stage 3: collect candidates with bits >= V ----------------

__global__ void k_collect(const float* c0, const float* c1, const float* c2,
                          const float* t0, const float* t1, const float* t2,
                          const unsigned int* vcut, unsigned int* counters,
                          unsigned long long* buf) {
    int level = blockIdx.z, img = blockIdx.y;
    const float* cls; const float* ctr; int hw;
    lvl_select(level, c0, c1, c2, t0, t1, t2, &cls, &ctr, &hw);
    int n = hw * NCLS;
    int pair = img * NLVL + level;
    const float* cl = cls + (size_t)img * n;
    const float* ct = ctr + (size_t)img * hw;
    unsigned int V = vcut[pair];
    for (int e = blockIdx.x * blockDim.x + threadIdx.x; e < n; e += gridDim.x * blockDim.x) {
        int a = e / NCLS;
        float s = sqrtf(sigm(cl[e]) * sigm(ct[a]));
        if (s > 0.2f) {
            unsigned int bits = __float_as_uint(s);
            if (bits >= V) {
                unsigned int slot = atomicAdd(&counters[pair], 1u);
                if (slot < CAP)
                    buf[(size_t)pair * CAP + slot] =
                        ((unsigned long long)bits << 32) | (unsigned int)(~(unsigned int)e);
            }
        }
    }
}

// ---------------- stage 4: per-(img,level) sort -> top-1000, decode boxes ----------------

__global__ void __launch_bounds__(1024)
k_sort_pairs(const unsigned long long* buf, const unsigned int* counters,
             const float* r0, const float* r1, const float* r2,
             const float* a0, const float* a1, const float* a2,
             float* cand_box, int* cand_lab, unsigned long long* gkey) {
    int pair = blockIdx.x;
    int img = pair / NLVL, level = pair % NLVL;
    __shared__ unsigned long long s[CAP];
    int cnt = (int)counters[pair]; if (cnt > CAP) cnt = CAP;
    for (int i = threadIdx.x; i < CAP; i += blockDim.x)
        s[i] = (i < cnt) ? buf[(size_t)pair * CAP + i] : 0ull;
    bitonic_desc(s, CAP);   // leading __syncthreads inside covers the load
    const float* reg; const float* anc; int hw;
    if (level == 0)      { reg = r0; anc = a0; hw = 4096; }
    else if (level == 1) { reg = r1; anc = a1; hw = 1024; }
    else                 { reg = r2; anc = a2; hw = 256; }
    const float* rg = reg + (size_t)img * hw * 4;
    for (int r = threadIdx.x; r < TOPK; r += blockDim.x) {
        unsigned long long key = s[r];
        int cpos = level * TOPK + r;
        size_t o = (size_t)img * NCAND + cpos;
        float b0 = 0, b1 = 0, b2 = 0, b3 = 0; int lab = 0; unsigned int bits = 0;
        if (key != 0ull) {
            bits = (unsigned int)(key >> 32);
            unsigned int idx = ~((unsigned int)key);
            int a = (int)(idx / NCLS); lab = (int)(idx % NCLS);
            float ax1 = anc[a * 4 + 0], ay1 = anc[a * 4 + 1];
            float ax2 = anc[a * 4 + 2], ay2 = anc[a * 4 + 3];
            float cx = 0.5f * (ax1 + ax2), cy = 0.5f * (ay1 + ay2);
            float w = ax2 - ax1, h = ay2 - ay1;
            float e0 = rg[a * 4 + 0] * w, e1 = rg[a * 4 + 1] * h;
            float e2 = rg[a * 4 + 2] * w, e3 = rg[a * 4 + 3] * h;
            b0 = fminf(fmaxf(cx - e0, 0.f), IMGSZ);
            b1 = fminf(fmaxf(cy - e1, 0.f), IMGSZ);
            b2 = fminf(fmaxf(cx + e2, 0.f), IMGSZ);
            b3 = fminf(fmaxf(cy + e3, 0.f), IMGSZ);
        }
        cand_box[o * 4 + 0] = b0; cand_box[o * 4 + 1] = b1;
        cand_box[o * 4 + 2] = b2; cand_box[o * 4 + 3] = b3;
        cand_lab[o] = lab;
        // global key: ties in bits break by smaller concat position (matches top_k)
        gkey[o] = ((unsigned long long)bits << 32) | (unsigned int)(~((unsigned int)cpos));
    }
}

// ---------------- stage 5 (fused): 3-way merge + greedy NMS prefix scan + output ----------------
//
// Key insight: output = first 100 kept candidates in global rank order (scores are
// sorted, so kept #101+ can never enter the top-100 of fsc). Suppression is sparse,
// so the greedy scan resolves in ~110 ranks. Kept boxes (offset coords + area) live
// in wave registers: lane l holds kept slots l and l+64. IoU formula is bit-identical
// to the round-1/2 mask kernel that validated absmax 0.0.

__global__ void __launch_bounds__(1024)
k_merge_nms(const unsigned long long* gkey, const float* cand_box, const int* cand_lab,
            float* out) {
    int img = blockIdx.x;
    int tid = threadIdx.x;
    __shared__ unsigned long long A[TOPK], B[TOPK], C[TOPK];
    __shared__ unsigned long long M[2 * TOPK];
    __shared__ unsigned long long S[NCAND];
    __shared__ float4 wbox[1024];
    __shared__ int    wlab[1024];
    __shared__ float4 kb[DETS]; __shared__ float ks[DETS]; __shared__ int kl[DETS];
    __shared__ float4 rb[DETS]; __shared__ int rl[DETS];

    const unsigned long long* G = gkey + (size_t)img * NCAND;
    for (int i = tid; i < TOPK; i += 1024) { A[i] = G[i]; B[i] = G[TOPK + i]; C[i] = G[2 * TOPK + i]; }
    __syncthreads();

    // merge-path A (1000) + B (1000) -> M (2000), descending, keys unique
    for (int k = tid; k < 2 * TOPK; k += 1024) {
        int lo = max(0, k - TOPK), hi = min(k, TOPK);
        while (lo < hi) {
            int mid = (lo + hi) >> 1;
            if (A[mid] > B[k - mid - 1]) lo = mid + 1; else hi = mid;
        }
        int i = lo, j = k - lo;
        unsigned long long av = (i < TOPK) ? A[i] : 0ull;
        unsigned long long bv = (j < TOPK) ? B[j] : 0ull;
        M[k] = (av > bv) ? av : bv;
    }
    __syncthreads();
    // merge-path M (2000) + C (1000) -> S (3000)
    for (int k = tid; k < NCAND; k += 1024) {
        int lo = max(0, k - TOPK), hi = min(k, 2 * TOPK);
        while (lo < hi) {
            int mid = (lo + hi) >> 1;
            if (M[mid] > C[k - mid - 1]) lo = mid + 1; else hi = mid;
        }
        int i = lo, j = k - lo;
        unsigned long long mv = (i < 2 * TOPK) ? M[i] : 0ull;
        unsigned long long cv = (j < TOPK) ? C[j] : 0ull;
        S[k] = (mv > cv) ? mv : cv;
    }
    __syncthreads();

    // gather candidate data for the first 1024 ranks into LDS
    const float4* CB4 = (const float4*)cand_box + (size_t)img * NCAND;
    const int* CL = cand_lab + (size_t)img * NCAND;
    {
        unsigned int pos = ~((unsigned int)S[tid]);
        wbox[tid] = CB4[pos];
        wlab[tid] = CL[pos];
    }
    __syncthreads();

    if (tid >= 64) return;   // single wave does the (short) serial scan
    int lane = tid;

    // kept-list registers: offset-space box + area; lane l owns slots l and l+64
    float aX1 = 0, aY1 = 0, aX2 = 0, aY2 = 0, aAR = 0;
    float bX1 = 0, bY1 = 0, bX2 = 0, bY2 = 0, bAR = 0;
    int kept = 0, ring = 0;

    for (int r = 0; r < NCAND && kept < DETS; ++r) {
        unsigned long long key = S[r];
        unsigned int bits = (unsigned int)(key >> 32);
        float4 bx; int lb;
        if (r < 1024) { bx = wbox[r]; lb = wlab[r]; }
        else { unsigned int pos = ~((unsigned int)key); bx = CB4[pos]; lb = CL[pos]; }

        if (bits != 0u) {           // positive score (> 0.2)
            float sc = __uint_as_float(bits);
            float off = (float)lb * (IMGSZ + 1.0f);
            float ox1 = bx.x + off, oy1 = bx.y + off;
            float ox2 = bx.z + off, oy2 = bx.w + off;
            float car = (ox2 - ox1) * (oy2 - oy1);
            bool sup = false;
            if (lane < kept) {      // slot lane
                float lx = fmaxf(aX1, ox1), ly = fmaxf(aY1, oy1);
                float rx = fminf(aX2, ox2), ry = fminf(aY2, oy2);
                float w = fmaxf(rx - lx, 0.f), h = fmaxf(ry - ly, 0.f);
                float inter = w * h;
                float iou = inter / (aAR + car - inter);
                sup = iou > 0.6f;
            }
            if (lane + 64 < kept) { // slot lane+64
                float lx = fmaxf(bX1, ox1), ly = fmaxf(bY1, oy1);
                float rx = fminf(bX2, ox2), ry = fminf(bY2, oy2);
                float w = fmaxf(rx - lx, 0.f), h = fmaxf(ry - ly, 0.f);
                float inter = w * h;
                float iou = inter / (bAR + car - inter);
                sup = sup || (iou > 0.6f);
            }
            unsigned long long m = __ballot(sup);
            if (m == 0ull) {        // kept
                if (kept < 64) {
                    if (lane == kept) { aX1 = ox1; aY1 = oy1; aX2 = ox2; aY2 = oy2; aAR = car; }
                } else {
                    if (lane == kept - 64) { bX1 = ox1; bY1 = oy1; bX2 = ox2; bY2 = oy2; bAR = car; }
                }
                if (lane == 0) { kb[kept] = bx; ks[kept] = sc; kl[kept] = lb; }
                kept++;
            } else if (ring < DETS) {   // suppressed: candidate for -1 padding
                if (lane == 0) { rb[ring] = bx; rl[ring] = lb; }
                ring++;
            }
        } else {                    // negative region (sorted: all the rest are too)
            if (ring < DETS) {
                if (lane == 0) { rb[ring] = bx; rl[ring] = lb; }
                ring++;
            }
            if (ring >= DETS) break;
        }
    }

    // write output: first `kept` entries, then -1 padding from earliest rejected ranks
    for (int k = lane; k < DETS; k += 64) {
        float4 bxo; float scv; int lv;
        if (k < kept) { bxo = kb[k]; scv = ks[k]; lv = kl[k]; }
        else { int q = k - kept; bxo = rb[q]; scv = -1.0f; lv = rl[q]; }
        float* ob = out + ((size_t)img * DETS + k) * 4;
        ob[0] = bxo.x; ob[1] = bxo.y; ob[2] = bxo.z; ob[3] = bxo.w;
        out[NIMG * DETS * 4 + img * DETS + k] = scv;
        out[NIMG * DETS * 5 + img * DETS + k] = (float)lv;
    }
}

// ---------------- launch ----------------

extern "C" void kernel_launch(void* const* d_in, const int* in_sizes, int n_in,
                              void* d_out, int out_size, void* d_ws, size_t ws_size,
                              hipStream_t stream) {
    (void)in_sizes; (void)n_in; (void)out_size; (void)ws_size;
    // setup_inputs() dict order: cls0, reg0, ctr0, anc0, cls1, reg1, ctr1, anc1, cls2, reg2, ctr2, anc2
    const float* cls0 = (const float*)d_in[0];
    const float* reg0 = (const float*)d_in[1];
    const float* ctr0 = (const float*)d_in[2];
    const float* anc0 = (const float*)d_in[3];
    const float* cls1 = (const float*)d_in[4];
    const float* reg1 = (const float*)d_in[5];
    const float* ctr1 = (const float*)d_in[6];
    const float* anc1 = (const float*)d_in[7];
    const float* cls2 = (const float*)d_in[8];
    const float* reg2 = (const float*)d_in[9];
    const float* ctr2 = (const float*)d_in[10];
    const float* anc2 = (const float*)d_in[11];
    float* out = (float*)d_out;
    char* ws = (char*)d_ws;

    // workspace layout (bytes)
    const size_t OFF_HIST = 0;                 // 24*8192*4   = 786432
    const size_t OFF_CNT  = 786432;            // 24*4
    const size_t OFF_VCUT = 786560;            // 24*4
    const size_t ZERO_B   = 786688;            // hist + counters (+vcut, harmless)
    const size_t OFF_BUF  = 786688;            // 24*2048*8   = 393216
    const size_t OFF_CBOX = 1179904;           // 8*3000*4*4  = 384000 (16B aligned)
    const size_t OFF_CLAB = 1563904;           // 8*3000*4    = 96000
    const size_t OFF_GKEY = 1659904;           // 8*3000*8    = 192000 -> total 1851904

    unsigned int* hist = (unsigned int*)(ws + OFF_HIST);
    unsigned int* cnt  = (unsigned int*)(ws + OFF_CNT);
    unsigned int* vcut = (unsigned int*)(ws + OFF_VCUT);
    unsigned long long* buf  = (unsigned long long*)(ws + OFF_BUF);
    float* cand_box = (float*)(ws + OFF_CBOX);
    int*   cand_lab = (int*)(ws + OFF_CLAB);
    unsigned long long* gkey = (unsigned long long*)(ws + OFF_GKEY);

    hipMemsetAsync(ws, 0, ZERO_B, stream);

    k_hist<<<dim3(16, NIMG, NLVL), 256, 0, stream>>>(cls0, cls1, cls2, ctr0, ctr1, ctr2, hist);
    k_find<<<24, 256, 0, stream>>>(hist, vcut);
    k_collect<<<dim3(64, NIMG, NLVL), 256, 0, stream>>>(cls0, cls1, cls2, ctr0, ctr1, ctr2,
                                                        vcut, cnt, buf);
    k_sort_pairs<<<24, 1024, 0, stream>>>(buf, cnt, reg0, reg1, reg2, anc0, anc1, anc2,
                                          cand_box, cand_lab, gkey);
    k_merge_nms<<<NIMG, 1024, 0, stream>>>(gkey, cand_box, cand_lab, out);
}

// Round 4
// 278.211 us; speedup vs baseline: 4.9454x; 1.0256x over previous
//
#include <hip/hip_runtime.h>

#define NCLS  80
#define TOPK  1000
#define NLVL  3
#define NIMG  8
#define NCAND 3000
#define DETS  100
#define CAP   2048          // cutoff-bin overshoot ~150-300 expected; 2048 = big margin
#define HBINS 4096          // q-space bins, 8192-ulp granules
#define NHBLK 16            // hist blocks per (img,level) pair
#define QBASE 0x3F800000u   // bits of q = 1.0 (q > 1 always)
#define QMAX  0x41C80000u   // bits of 25.0; q < 25  <=>  s > 0.2
#define IMGSZ 2048.0f

// ---------------- helpers ----------------

__device__ __forceinline__ float sigm(float x) {
    if (x >= 0.f) return 1.f / (1.f + expf(-x));
    float e = expf(x);
    return e / (1.f + e);
}

// q = (1+e^-a)(1+e^-b), rounding pinned (identical bits in k_hist and k_collect)
__device__ __forceinline__ unsigned int qbits(float ea, float t1) {
    return __float_as_uint(__fmul_rn(__fadd_rn(1.f, ea), t1));
}

// descending bitonic sort of N u64 keys in LDS (N power of 2, N >= blockDim)
__device__ __forceinline__ void bitonic_desc(unsigned long long* s, int N) {
    for (int k = 2; k <= N; k <<= 1) {
        for (int j = k >> 1; j > 0; j >>= 1) {
            __syncthreads();
            for (int i = threadIdx.x; i < N; i += blockDim.x) {
                int ixj = i ^ j;
                if (ixj > i) {
                    unsigned long long a = s[i], b = s[ixj];
                    bool up = ((i & k) == 0);
                    if (up ? (a < b) : (a > b)) { s[i] = b; s[ixj] = a; }
                }
            }
        }
    }
    __syncthreads();
}

__device__ __forceinline__ void lvl_select(int level,
    const float* c0, const float* c1, const float* c2,
    const float* t0, const float* t1, const float* t2,
    const float** cls, const float** ctr, int* hw) {
    if (level == 0)      { *cls = c0; *ctr = t0; *hw = 4096; }
    else if (level == 1) { *cls = c1; *ctr = t1; *hw = 1024; }
    else                 { *cls = c2; *ctr = t2; *hw = 256; }
}

// ---------------- stage 1: per-block partial histograms of q bits ----------------

__global__ void k_hist(const float* c0, const float* c1, const float* c2,
                       const float* t0, const float* t1, const float* t2,
                       unsigned int* parts) {
    int level = blockIdx.z, img = blockIdx.y;
    const float* cls; const float* ctr; int hw;
    lvl_select(level, c0, c1, c2, t0, t1, t2, &cls, &ctr, &hw);
    int n4 = hw * (NCLS / 4);          // float4 granules; 4 classes share one anchor
    const float4* cl4 = (const float4*)(cls + (size_t)img * hw * NCLS);
    const float* ct = ctr + (size_t)img * hw;
    __shared__ unsigned int h[HBINS];
    for (int i = threadIdx.x; i < HBINS; i += 256) h[i] = 0;
    __syncthreads();
    for (int i = blockIdx.x * 256 + threadIdx.x; i < n4; i += NHBLK * 256) {
        float4 v = cl4[i];
        int a = i / (NCLS / 4);        // 20 float4 per anchor row
        float eb = expf(-ct[a]);
        float t1 = __fadd_rn(1.f, eb);
        #pragma unroll
        for (int k = 0; k < 4; ++k) {
            float x = (k == 0) ? v.x : (k == 1) ? v.y : (k == 2) ? v.z : v.w;
            unsigned int qb = qbits(expf(-x), t1);
            if (qb < QMAX) {
                unsigned int bin = (qb - QBASE) >> 13;
                if (bin > HBINS - 1) bin = HBINS - 1;
                atomicAdd(&h[bin], 1u);
            }
        }
    }
    __syncthreads();
    unsigned int* P = parts + ((size_t)((img * NLVL + level) * NHBLK + blockIdx.x)) * HBINS;
    for (int i = threadIdx.x; i < HBINS; i += 256) P[i] = h[i];   // coalesced, no atomics
}

// ---------------- stage 2: merge partials + find cutoff V per (img,level) ----------------
// q ascending == score descending: scan from bin 0 upward.

__global__ void k_find(const unsigned int* parts, unsigned int* vcut) {
    int pair = blockIdx.x;
    int tid = threadIdx.x;      // 256 threads
    __shared__ unsigned int hb[HBINS];
    __shared__ unsigned int segsum[256];
    __shared__ unsigned int pref[256];
    unsigned int acc[HBINS / 256];
    #pragma unroll
    for (int j = 0; j < HBINS / 256; ++j) acc[j] = 0;
    for (int blk = 0; blk < NHBLK; ++blk) {
        const unsigned int* P = parts + ((size_t)(pair * NHBLK + blk)) * HBINS;
        #pragma unroll
        for (int j = 0; j < HBINS / 256; ++j) acc[j] += P[tid + 256 * j];
    }
    #pragma unroll
    for (int j = 0; j < HBINS / 256; ++j) hb[tid + 256 * j] = acc[j];
    __syncthreads();
    unsigned int seg = 0;
    #pragma unroll
    for (int j = 0; j < 16; ++j) seg += hb[16 * tid + j];   // thread owns bins [16t,16t+16)
    segsum[tid] = seg;
    pref[tid] = seg;
    __syncthreads();
    for (int off = 1; off < 256; off <<= 1) {
        unsigned int v = (tid >= off) ? pref[tid - off] : 0u;
        __syncthreads();
        pref[tid] += v;
        __syncthreads();
    }
    unsigned int incl = pref[tid];
    unsigned int excl = incl - seg;
    if (excl < (unsigned int)TOPK && incl >= (unsigned int)TOPK) {
        unsigned int cum = excl; int B = HBINS - 1;
        for (int b = 16 * tid; b < 16 * tid + 16; ++b) {
            cum += hb[b];
            if (cum >= (unsigned int)TOPK) { B = b; break; }
        }
        vcut[pair] = (B >= HBINS - 1) ? QMAX : (QBASE + ((unsigned int)(B + 1) << 13));
    }
    if (tid == 255 && pref[255] < (unsigned int)TOPK)
        vcut[pair] = QMAX;   // fewer than TOPK pass threshold: collect all passing
}

// ---------------- stage 3: collect candidates with q_bits < V; exact s for survivors ----------------

__global__ void k_collect(const float* c0, const float* c1, const float* c2,
                          const float* t0, const float* t1, const float* t2,
                          const unsigned int* vcut, unsigned int* counters,
                          unsigned long long* buf) {
    int level = blockIdx.z, img = blockIdx.y;
    const float* cls; const float* ctr; int hw;
    lvl_select(level, c0, c1, c2, t0, t1, t2, &cls, &ctr, &hw);
    int n4 = hw * (NCLS / 4);
    int pair = img * NLVL + level;
    const float4* cl4 = (const float4*)(cls + (size_t)img * hw * NCLS);
    const float* ct = ctr + (size_t)img * hw;
    unsigned int V = vcut[pair];
    for (int i = blockIdx.x * 256 + threadIdx.x; i < n4; i += 32 * 256) {
        float4 v = cl4[i];
        int a = i / (NCLS / 4);
        float cta = ct[a];
        float eb = expf(-cta);
        float t1 = __fadd_rn(1.f, eb);
        #pragma unroll
        for (int k = 0; k < 4; ++k) {
            float x = (k == 0) ? v.x : (k == 1) ? v.y : (k == 2) ? v.z : v.w;
            unsigned int qb = qbits(expf(-x), t1);
            if (qb < V) {
                // exact score, bit-identical to rounds 1-3 (validated absmax 0.0)
                float s = sqrtf(sigm(x) * sigm(cta));
                unsigned int e = (unsigned int)(4 * i + k);
                unsigned int slot = atomicAdd(&counters[pair], 1u);
                if (slot < CAP)
                    buf[(size_t)pair * CAP + slot] =
                        ((unsigned long long)__float_as_uint(s) << 32) | (~e);
            }
        }
    }
}

// ---------------- stage 4: per-(img,level) sort -> top-1000, decode boxes ----------------

__global__ void __launch_bounds__(1024)
k_sort_pairs(const unsigned long long* buf, const unsigned int* counters,
             const float* r0, const float* r1, const float* r2,
             const float* a0, const float* a1, const float* a2,
             float* cand_box, int* cand_lab, unsigned long long* gkey) {
    int pair = blockIdx.x;
    int img = pair / NLVL, level = pair % NLVL;
    __shared__ unsigned long long s[CAP];
    int cnt = (int)counters[pair]; if (cnt > CAP) cnt = CAP;
    for (int i = threadIdx.x; i < CAP; i += blockDim.x)
        s[i] = (i < cnt) ? buf[(size_t)pair * CAP + i] : 0ull;
    bitonic_desc(s, CAP);   // leading __syncthreads inside covers the load
    const float* reg; const float* anc; int hw;
    if (level == 0)      { reg = r0; anc = a0; hw = 4096; }
    else if (level == 1) { reg = r1; anc = a1; hw = 1024; }
    else                 { reg = r2; anc = a2; hw = 256; }
    const float* rg = reg + (size_t)img * hw * 4;
    for (int r = threadIdx.x; r < TOPK; r += blockDim.x) {
        unsigned long long key = s[r];
        int cpos = level * TOPK + r;
        size_t o = (size_t)img * NCAND + cpos;
        float b0 = 0, b1 = 0, b2 = 0, b3 = 0; int lab = 0; unsigned int bits = 0;
        if (key != 0ull) {
            bits = (unsigned int)(key >> 32);
            unsigned int idx = ~((unsigned int)key);
            int a = (int)(idx / NCLS); lab = (int)(idx % NCLS);
            float ax1 = anc[a * 4 + 0], ay1 = anc[a * 4 + 1];
            float ax2 = anc[a * 4 + 2], ay2 = anc[a * 4 + 3];
            float cx = 0.5f * (ax1 + ax2), cy = 0.5f * (ay1 + ay2);
            float w = ax2 - ax1, h = ay2 - ay1;
            float e0 = rg[a * 4 + 0] * w, e1 = rg[a * 4 + 1] * h;
            float e2 = rg[a * 4 + 2] * w, e3 = rg[a * 4 + 3] * h;
            b0 = fminf(fmaxf(cx - e0, 0.f), IMGSZ);
            b1 = fminf(fmaxf(cy - e1, 0.f), IMGSZ);
            b2 = fminf(fmaxf(cx + e2, 0.f), IMGSZ);
            b3 = fminf(fmaxf(cy + e3, 0.f), IMGSZ);
        }
        cand_box[o * 4 + 0] = b0; cand_box[o * 4 + 1] = b1;
        cand_box[o * 4 + 2] = b2; cand_box[o * 4 + 3] = b3;
        cand_lab[o] = lab;
        // global key: ties in bits break by smaller concat position (matches top_k)
        gkey[o] = ((unsigned long long)bits << 32) | (unsigned int)(~((unsigned int)cpos));
    }
}

// ---------------- stage 5 (fused): 3-way merge + greedy NMS prefix scan + output ----------------
//
// Output = first 100 kept candidates in global rank order (scores sorted, so kept
// #101+ can never enter the top-100 of fsc). Suppression is sparse, so the greedy
// scan resolves in ~110 ranks. Kept boxes (offset coords + area) live in wave
// registers: lane l holds kept slots l and l+64.

__global__ void __launch_bounds__(1024)
k_merge_nms(const unsigned long long* gkey, const float* cand_box, const int* cand_lab,
            float* out) {
    int img = blockIdx.x;
    int tid = threadIdx.x;
    __shared__ unsigned long long A[TOPK], B[TOPK], C[TOPK];
    __shared__ unsigned long long M[2 * TOPK];
    __shared__ unsigned long long S[NCAND];
    __shared__ float4 wbox[1024];
    __shared__ int    wlab[1024];
    __shared__ float4 kb[DETS]; __shared__ float ks[DETS]; __shared__ int kl[DETS];
    __shared__ float4 rb[DETS]; __shared__ int rl[DETS];

    const unsigned long long* G = gkey + (size_t)img * NCAND;
    for (int i = tid; i < TOPK; i += 1024) { A[i] = G[i]; B[i] = G[TOPK + i]; C[i] = G[2 * TOPK + i]; }
    __syncthreads();

    // merge-path A (1000) + B (1000) -> M (2000), descending, keys unique
    for (int k = tid; k < 2 * TOPK; k += 1024) {
        int lo = max(0, k - TOPK), hi = min(k, TOPK);
        while (lo < hi) {
            int mid = (lo + hi) >> 1;
            if (A[mid] > B[k - mid - 1]) lo = mid + 1; else hi = mid;
        }
        int i = lo, j = k - lo;
        unsigned long long av = (i < TOPK) ? A[i] : 0ull;
        unsigned long long bv = (j < TOPK) ? B[j] : 0ull;
        M[k] = (av > bv) ? av : bv;
    }
    __syncthreads();
    // merge-path M (2000) + C (1000) -> S (3000)
    for (int k = tid; k < NCAND; k += 1024) {
        int lo = max(0, k - TOPK), hi = min(k, 2 * TOPK);
        while (lo < hi) {
            int mid = (lo + hi) >> 1;
            if (M[mid] > C[k - mid - 1]) lo = mid + 1; else hi = mid;
        }
        int i = lo, j = k - lo;
        unsigned long long mv = (i < 2 * TOPK) ? M[i] : 0ull;
        unsigned long long cv = (j < TOPK) ? C[j] : 0ull;
        S[k] = (mv > cv) ? mv : cv;
    }
    __syncthreads();

    // gather candidate data for the first 1024 ranks into LDS
    const float4* CB4 = (const float4*)cand_box + (size_t)img * NCAND;
    const int* CL = cand_lab + (size_t)img * NCAND;
    {
        unsigned int pos = ~((unsigned int)S[tid]);
        wbox[tid] = CB4[pos];
        wlab[tid] = CL[pos];
    }
    __syncthreads();

    if (tid >= 64) return;   // single wave does the (short) serial scan
    int lane = tid;

    float aX1 = 0, aY1 = 0, aX2 = 0, aY2 = 0, aAR = 0;
    float bX1 = 0, bY1 = 0, bX2 = 0, bY2 = 0, bAR = 0;
    int kept = 0, ring = 0;

    for (int r = 0; r < NCAND && kept < DETS; ++r) {
        unsigned long long key = S[r];
        unsigned int bits = (unsigned int)(key >> 32);
        float4 bx; int lb;
        if (r < 1024) { bx = wbox[r]; lb = wlab[r]; }
        else { unsigned int pos = ~((unsigned int)key); bx = CB4[pos]; lb = CL[pos]; }

        if (bits != 0u) {           // positive score (> 0.2)
            float sc = __uint_as_float(bits);
            float off = (float)lb * (IMGSZ + 1.0f);
            float ox1 = bx.x + off, oy1 = bx.y + off;
            float ox2 = bx.z + off, oy2 = bx.w + off;
            float car = (ox2 - ox1) * (oy2 - oy1);
            bool sup = false;
            if (lane < kept) {
                float lx = fmaxf(aX1, ox1), ly = fmaxf(aY1, oy1);
                float rx = fminf(aX2, ox2), ry = fminf(aY2, oy2);
                float w = fmaxf(rx - lx, 0.f), h = fmaxf(ry - ly, 0.f);
                float inter = w * h;
                float iou = inter / (aAR + car - inter);
                sup = iou > 0.6f;
            }
            if (lane + 64 < kept) {
                float lx = fmaxf(bX1, ox1), ly = fmaxf(bY1, oy1);
                float rx = fminf(bX2, ox2), ry = fminf(bY2, oy2);
                float w = fmaxf(rx - lx, 0.f), h = fmaxf(ry - ly, 0.f);
                float inter = w * h;
                float iou = inter / (bAR + car - inter);
                sup = sup || (iou > 0.6f);
            }
            unsigned long long m = __ballot(sup);
            if (m == 0ull) {        // kept
                if (kept < 64) {
                    if (lane == kept) { aX1 = ox1; aY1 = oy1; aX2 = ox2; aY2 = oy2; aAR = car; }
                } else {
                    if (lane == kept - 64) { bX1 = ox1; bY1 = oy1; bX2 = ox2; bY2 = oy2; bAR = car; }
                }
                if (lane == 0) { kb[kept] = bx; ks[kept] = sc; kl[kept] = lb; }
                kept++;
            } else if (ring < DETS) {   // suppressed: candidate for -1 padding
                if (lane == 0) { rb[ring] = bx; rl[ring] = lb; }
                ring++;
            }
        } else {                    // negative region (sorted: all the rest are too)
            if (ring < DETS) {
                if (lane == 0) { rb[ring] = bx; rl[ring] = lb; }
                ring++;
            }
            if (ring >= DETS) break;
        }
    }

    for (int k = lane; k < DETS; k += 64) {
        float4 bxo; float scv; int lv;
        if (k < kept) { bxo = kb[k]; scv = ks[k]; lv = kl[k]; }
        else { int q = k - kept; bxo = rb[q]; scv = -1.0f; lv = rl[q]; }
        float* ob = out + ((size_t)img * DETS + k) * 4;
        ob[0] = bxo.x; ob[1] = bxo.y; ob[2] = bxo.z; ob[3] = bxo.w;
        out[NIMG * DETS * 4 + img * DETS + k] = scv;
        out[NIMG * DETS * 5 + img * DETS + k] = (float)lv;
    }
}

// ---------------- launch ----------------

extern "C" void kernel_launch(void* const* d_in, const int* in_sizes, int n_in,
                              void* d_out, int out_size, void* d_ws, size_t ws_size,
                              hipStream_t stream) {
    (void)in_sizes; (void)n_in; (void)out_size; (void)ws_size;
    // setup_inputs() dict order: cls0, reg0, ctr0, anc0, cls1, reg1, ctr1, anc1, cls2, reg2, ctr2, anc2
    const float* cls0 = (const float*)d_in[0];
    const float* reg0 = (const float*)d_in[1];
    const float* ctr0 = (const float*)d_in[2];
    const float* anc0 = (const float*)d_in[3];
    const float* cls1 = (const float*)d_in[4];
    const float* reg1 = (const float*)d_in[5];
    const float* ctr1 = (const float*)d_in[6];
    const float* anc1 = (const float*)d_in[7];
    const float* cls2 = (const float*)d_in[8];
    const float* reg2 = (const float*)d_in[9];
    const float* ctr2 = (const float*)d_in[10];
    const float* anc2 = (const float*)d_in[11];
    float* out = (float*)d_out;
    char* ws = (char*)d_ws;

    // workspace layout (bytes)
    const size_t OFF_PARTS = 0;          // 24*16*4096*4 = 6,291,456 (fully overwritten; no memset)
    const size_t OFF_CNT   = 6291456;    // 24*4 = 96 -> pad
    const size_t ZERO_OFF  = 6291456;
    const size_t ZERO_B    = 128;        // counters only
    const size_t OFF_VCUT  = 6291584;    // 24*4
    const size_t OFF_BUF   = 6291712;    // 24*2048*8  = 393,216
    const size_t OFF_CBOX  = 6684928;    // 8*3000*4*4 = 384,000 (16B aligned)
    const size_t OFF_CLAB  = 7068928;    // 8*3000*4   = 96,000
    const size_t OFF_GKEY  = 7164928;    // 8*3000*8   = 192,000 -> total 7,356,928

    unsigned int* parts = (unsigned int*)(ws + OFF_PARTS);
    unsigned int* cnt   = (unsigned int*)(ws + OFF_CNT);
    unsigned int* vcut  = (unsigned int*)(ws + OFF_VCUT);
    unsigned long long* buf  = (unsigned long long*)(ws + OFF_BUF);
    float* cand_box = (float*)(ws + OFF_CBOX);
    int*   cand_lab = (int*)(ws + OFF_CLAB);
    unsigned long long* gkey = (unsigned long long*)(ws + OFF_GKEY);

    hipMemsetAsync(ws + ZERO_OFF, 0, ZERO_B, stream);

    k_hist<<<dim3(NHBLK, NIMG, NLVL), 256, 0, stream>>>(cls0, cls1, cls2, ctr0, ctr1, ctr2, parts);
    k_find<<<24, 256, 0, stream>>>(parts, vcut);
    k_collect<<<dim3(32, NIMG, NLVL), 256, 0, stream>>>(cls0, cls1, cls2, ctr0, ctr1, ctr2,
                                                        vcut, cnt, buf);
    k_sort_pairs<<<24, 1024, 0, stream>>>(buf, cnt, reg0, reg1, reg2, anc0, anc1, anc2,
                                          cand_box, cand_lab, gkey);
    k_merge_nms<<<NIMG, 1024, 0, stream>>>(gkey, cand_box, cand_lab, out);
}

// Round 5
// 197.747 us; speedup vs baseline: 6.9577x; 1.4069x over previous
//
#include <hip/hip_runtime.h>

#define NCLS  80
#define TOPK  1000
#define NLVL  3
#define NIMG  8
#define NCAND 3000
#define DETS  100
#define CAP   2048          // cutoff-bin overshoot ~150-300 expected; 2048 = big margin
#define HBINS 4096          // q-space bins, 8192-ulp granules
#define NHBLK 16            // hist blocks per (img,level) pair
#define NCBLK 64            // collect blocks per (img,level) pair
#define QBASE 0x3F800000u   // bits of q = 1.0 (q > 1 always)
#define QMAX  0x41C80000u   // bits of 25.0; q < 25  <=>  s > 0.2
#define IMGSZ 2048.0f

// ---------------- helpers ----------------

__device__ __forceinline__ float sigm(float x) {
    if (x >= 0.f) return 1.f / (1.f + expf(-x));
    float e = expf(x);
    return e / (1.f + e);
}

// q = (1+e^-a)(1+e^-b), rounding pinned (identical bits in k_hist and k_collect)
__device__ __forceinline__ unsigned int qbits(float ea, float t1) {
    return __float_as_uint(__fmul_rn(__fadd_rn(1.f, ea), t1));
}

// descending bitonic sort of N u64 keys in LDS (N power of 2, N >= blockDim)
__device__ __forceinline__ void bitonic_desc(unsigned long long* s, int N) {
    for (int k = 2; k <= N; k <<= 1) {
        for (int j = k >> 1; j > 0; j >>= 1) {
            __syncthreads();
            for (int i = threadIdx.x; i < N; i += blockDim.x) {
                int ixj = i ^ j;
                if (ixj > i) {
                    unsigned long long a = s[i], b = s[ixj];
                    bool up = ((i & k) == 0);
                    if (up ? (a < b) : (a > b)) { s[i] = b; s[ixj] = a; }
                }
            }
        }
    }
    __syncthreads();
}

__device__ __forceinline__ void lvl_select(int level,
    const float* c0, const float* c1, const float* c2,
    const float* t0, const float* t1, const float* t2,
    const float** cls, const float** ctr, int* hw) {
    if (level == 0)      { *cls = c0; *ctr = t0; *hw = 4096; }
    else if (level == 1) { *cls = c1; *ctr = t1; *hw = 1024; }
    else                 { *cls = c2; *ctr = t2; *hw = 256; }
}

// ---------------- stage 1: per-block partial histograms of q bits ----------------

__global__ void k_hist(const float* c0, const float* c1, const float* c2,
                       const float* t0, const float* t1, const float* t2,
                       unsigned int* parts) {
    int level = blockIdx.z, img = blockIdx.y;
    const float* cls; const float* ctr; int hw;
    lvl_select(level, c0, c1, c2, t0, t1, t2, &cls, &ctr, &hw);
    int n4 = hw * (NCLS / 4);          // float4 granules; 4 classes share one anchor
    const float4* cl4 = (const float4*)(cls + (size_t)img * hw * NCLS);
    const float* ct = ctr + (size_t)img * hw;
    __shared__ unsigned int h[HBINS];
    for (int i = threadIdx.x; i < HBINS; i += 256) h[i] = 0;
    __syncthreads();
    for (int i = blockIdx.x * 256 + threadIdx.x; i < n4; i += NHBLK * 256) {
        float4 v = cl4[i];
        int a = i / (NCLS / 4);        // 20 float4 per anchor row
        float eb = expf(-ct[a]);
        float t1 = __fadd_rn(1.f, eb);
        #pragma unroll
        for (int k = 0; k < 4; ++k) {
            float x = (k == 0) ? v.x : (k == 1) ? v.y : (k == 2) ? v.z : v.w;
            unsigned int qb = qbits(expf(-x), t1);
            if (qb < QMAX) {
                unsigned int bin = (qb - QBASE) >> 13;
                if (bin > HBINS - 1) bin = HBINS - 1;
                atomicAdd(&h[bin], 1u);
            }
        }
    }
    __syncthreads();
    unsigned int* P = parts + ((size_t)((img * NLVL + level) * NHBLK + blockIdx.x)) * HBINS;
    for (int i = threadIdx.x; i < HBINS; i += 256) P[i] = h[i];   // coalesced, no atomics
}

// ---------------- stage 2: merge partials + find cutoff V per (img,level) ----------------
// q ascending == score descending: scan from bin 0 upward.

__global__ void k_find(const unsigned int* parts, unsigned int* vcut) {
    int pair = blockIdx.x;
    int tid = threadIdx.x;      // 256 threads
    __shared__ unsigned int hb[HBINS];
    __shared__ unsigned int segsum[256];
    __shared__ unsigned int pref[256];
    unsigned int acc[HBINS / 256];
    #pragma unroll
    for (int j = 0; j < HBINS / 256; ++j) acc[j] = 0;
    for (int blk = 0; blk < NHBLK; ++blk) {
        const unsigned int* P = parts + ((size_t)(pair * NHBLK + blk)) * HBINS;
        #pragma unroll
        for (int j = 0; j < HBINS / 256; ++j) acc[j] += P[tid + 256 * j];
    }
    #pragma unroll
    for (int j = 0; j < HBINS / 256; ++j) hb[tid + 256 * j] = acc[j];
    __syncthreads();
    unsigned int seg = 0;
    #pragma unroll
    for (int j = 0; j < 16; ++j) seg += hb[16 * tid + j];   // thread owns bins [16t,16t+16)
    segsum[tid] = seg;
    pref[tid] = seg;
    __syncthreads();
    for (int off = 1; off < 256; off <<= 1) {
        unsigned int v = (tid >= off) ? pref[tid - off] : 0u;
        __syncthreads();
        pref[tid] += v;
        __syncthreads();
    }
    unsigned int incl = pref[tid];
    unsigned int excl = incl - seg;
    if (excl < (unsigned int)TOPK && incl >= (unsigned int)TOPK) {
        unsigned int cum = excl; int B = HBINS - 1;
        for (int b = 16 * tid; b < 16 * tid + 16; ++b) {
            cum += hb[b];
            if (cum >= (unsigned int)TOPK) { B = b; break; }
        }
        vcut[pair] = (B >= HBINS - 1) ? QMAX : (QBASE + ((unsigned int)(B + 1) << 13));
    }
    if (tid == 255 && pref[255] < (unsigned int)TOPK)
        vcut[pair] = QMAX;   // fewer than TOPK pass threshold: collect all passing
}

// ---------------- stage 3: collect candidates with q_bits < V ----------------
// Survivors staged in LDS (fast local atomics); ONE global atomic per block
// (round-4 postmortem: 36k same-cacheline device atomics serialized ~85 us).
// Slot order within buf is irrelevant: k_sort_pairs sorts by the full key.

__global__ void k_collect(const float* c0, const float* c1, const float* c2,
                          const float* t0, const float* t1, const float* t2,
                          const unsigned int* vcut, unsigned int* counters,
                          unsigned long long* buf) {
    int level = blockIdx.z, img = blockIdx.y;
    const float* cls; const float* ctr; int hw;
    lvl_select(level, c0, c1, c2, t0, t1, t2, &cls, &ctr, &hw);
    int n4 = hw * (NCLS / 4);
    int pair = img * NLVL + level;
    const float4* cl4 = (const float4*)(cls + (size_t)img * hw * NCLS);
    const float* ct = ctr + (size_t)img * hw;
    unsigned int V = vcut[pair];
    __shared__ unsigned long long sbuf[2048];
    __shared__ unsigned int scnt;
    __shared__ unsigned int sbase;
    if (threadIdx.x == 0) scnt = 0;
    __syncthreads();
    for (int i = blockIdx.x * 256 + threadIdx.x; i < n4; i += NCBLK * 256) {
        float4 v = cl4[i];
        int a = i / (NCLS / 4);
        float cta = ct[a];
        float eb = expf(-cta);
        float t1 = __fadd_rn(1.f, eb);
        #pragma unroll
        for (int k = 0; k < 4; ++k) {
            float x = (k == 0) ? v.x : (k == 1) ? v.y : (k == 2) ? v.z : v.w;
            unsigned int qb = qbits(expf(-x), t1);
            if (qb < V) {
                // exact score, bit-identical to rounds 1-4 (validated absmax 0.0)
                float s = sqrtf(sigm(x) * sigm(cta));
                unsigned int e = (unsigned int)(4 * i + k);
                unsigned int slot = atomicAdd(&scnt, 1u);   // LDS atomic, sparse
                if (slot < 2048)
                    sbuf[slot] = ((unsigned long long)__float_as_uint(s) << 32) | (~e);
            }
        }
    }
    __syncthreads();
    unsigned int cl_n = scnt; if (cl_n > 2048) cl_n = 2048;
    if (threadIdx.x == 0)
        sbase = atomicAdd(&counters[pair * 16], cl_n);      // one global atomic/block
    __syncthreads();
    unsigned int base = sbase;
    for (unsigned int idx = threadIdx.x; idx < cl_n; idx += 256) {
        unsigned int g = base + idx;
        if (g < CAP) buf[(size_t)pair * CAP + g] = sbuf[idx];   // coalesced flush
    }
}

// ---------------- stage 4: per-(img,level) sort -> top-1000, decode boxes ----------------

__global__ void __launch_bounds__(1024)
k_sort_pairs(const unsigned long long* buf, const unsigned int* counters,
             const float* r0, const float* r1, const float* r2,
             const float* a0, const float* a1, const float* a2,
             float* cand_box, int* cand_lab, unsigned long long* gkey) {
    int pair = blockIdx.x;
    int img = pair / NLVL, level = pair % NLVL;
    __shared__ unsigned long long s[CAP];
    int cnt = (int)counters[pair * 16]; if (cnt > CAP) cnt = CAP;
    for (int i = threadIdx.x; i < CAP; i += blockDim.x)
        s[i] = (i < cnt) ? buf[(size_t)pair * CAP + i] : 0ull;
    bitonic_desc(s, CAP);   // leading __syncthreads inside covers the load
    const float* reg; const float* anc; int hw;
    if (level == 0)      { reg = r0; anc = a0; hw = 4096; }
    else if (level == 1) { reg = r1; anc = a1; hw = 1024; }
    else                 { reg = r2; anc = a2; hw = 256; }
    const float* rg = reg + (size_t)img * hw * 4;
    for (int r = threadIdx.x; r < TOPK; r += blockDim.x) {
        unsigned long long key = s[r];
        int cpos = level * TOPK + r;
        size_t o = (size_t)img * NCAND + cpos;
        float b0 = 0, b1 = 0, b2 = 0, b3 = 0; int lab = 0; unsigned int bits = 0;
        if (key != 0ull) {
            bits = (unsigned int)(key >> 32);
            unsigned int idx = ~((unsigned int)key);
            int a = (int)(idx / NCLS); lab = (int)(idx % NCLS);
            float ax1 = anc[a * 4 + 0], ay1 = anc[a * 4 + 1];
            float ax2 = anc[a * 4 + 2], ay2 = anc[a * 4 + 3];
            float cx = 0.5f * (ax1 + ax2), cy = 0.5f * (ay1 + ay2);
            float w = ax2 - ax1, h = ay2 - ay1;
            float e0 = rg[a * 4 + 0] * w, e1 = rg[a * 4 + 1] * h;
            float e2 = rg[a * 4 + 2] * w, e3 = rg[a * 4 + 3] * h;
            b0 = fminf(fmaxf(cx - e0, 0.f), IMGSZ);
            b1 = fminf(fmaxf(cy - e1, 0.f), IMGSZ);
            b2 = fminf(fmaxf(cx + e2, 0.f), IMGSZ);
            b3 = fminf(fmaxf(cy + e3, 0.f), IMGSZ);
        }
        cand_box[o * 4 + 0] = b0; cand_box[o * 4 + 1] = b1;
        cand_box[o * 4 + 2] = b2; cand_box[o * 4 + 3] = b3;
        cand_lab[o] = lab;
        // global key: ties in bits break by smaller concat position (matches top_k)
        gkey[o] = ((unsigned long long)bits << 32) | (unsigned int)(~((unsigned int)cpos));
    }
}

// ---------------- stage 5 (fused): 3-way merge + greedy NMS prefix scan + output ----------------
//
// Output = first 100 kept candidates in global rank order (scores sorted, so kept
// #101+ can never enter the top-100 of fsc). Suppression is sparse, so the greedy
// scan resolves in ~110 ranks. Kept boxes (offset coords + area) live in wave
// registers: lane l holds kept slots l and l+64.

__global__ void __launch_bounds__(1024)
k_merge_nms(const unsigned long long* gkey, const float* cand_box, const int* cand_lab,
            float* out) {
    int img = blockIdx.x;
    int tid = threadIdx.x;
    __shared__ unsigned long long A[TOPK], B[TOPK], C[TOPK];
    __shared__ unsigned long long M[2 * TOPK];
    __shared__ unsigned long long S[NCAND];
    __shared__ float4 wbox[1024];
    __shared__ int    wlab[1024];
    __shared__ float4 kb[DETS]; __shared__ float ks[DETS]; __shared__ int kl[DETS];
    __shared__ float4 rb[DETS]; __shared__ int rl[DETS];

    const unsigned long long* G = gkey + (size_t)img * NCAND;
    for (int i = tid; i < TOPK; i += 1024) { A[i] = G[i]; B[i] = G[TOPK + i]; C[i] = G[2 * TOPK + i]; }
    __syncthreads();

    // merge-path A (1000) + B (1000) -> M (2000), descending, keys unique
    for (int k = tid; k < 2 * TOPK; k += 1024) {
        int lo = max(0, k - TOPK), hi = min(k, TOPK);
        while (lo < hi) {
            int mid = (lo + hi) >> 1;
            if (A[mid] > B[k - mid - 1]) lo = mid + 1; else hi = mid;
        }
        int i = lo, j = k - lo;
        unsigned long long av = (i < TOPK) ? A[i] : 0ull;
        unsigned long long bv = (j < TOPK) ? B[j] : 0ull;
        M[k] = (av > bv) ? av : bv;
    }
    __syncthreads();
    // merge-path M (2000) + C (1000) -> S (3000)
    for (int k = tid; k < NCAND; k += 1024) {
        int lo = max(0, k - TOPK), hi = min(k, 2 * TOPK);
        while (lo < hi) {
            int mid = (lo + hi) >> 1;
            if (M[mid] > C[k - mid - 1]) lo = mid + 1; else hi = mid;
        }
        int i = lo, j = k - lo;
        unsigned long long mv = (i < 2 * TOPK) ? M[i] : 0ull;
        unsigned long long cv = (j < TOPK) ? C[j] : 0ull;
        S[k] = (mv > cv) ? mv : cv;
    }
    __syncthreads();

    // gather candidate data for the first 1024 ranks into LDS
    const float4* CB4 = (const float4*)cand_box + (size_t)img * NCAND;
    const int* CL = cand_lab + (size_t)img * NCAND;
    {
        unsigned int pos = ~((unsigned int)S[tid]);
        wbox[tid] = CB4[pos];
        wlab[tid] = CL[pos];
    }
    __syncthreads();

    if (tid >= 64) return;   // single wave does the (short) serial scan
    int lane = tid;

    float aX1 = 0, aY1 = 0, aX2 = 0, aY2 = 0, aAR = 0;
    float bX1 = 0, bY1 = 0, bX2 = 0, bY2 = 0, bAR = 0;
    int kept = 0, ring = 0;

    for (int r = 0; r < NCAND && kept < DETS; ++r) {
        unsigned long long key = S[r];
        unsigned int bits = (unsigned int)(key >> 32);
        float4 bx; int lb;
        if (r < 1024) { bx = wbox[r]; lb = wlab[r]; }
        else { unsigned int pos = ~((unsigned int)key); bx = CB4[pos]; lb = CL[pos]; }

        if (bits != 0u) {           // positive score (> 0.2)
            float sc = __uint_as_float(bits);
            float off = (float)lb * (IMGSZ + 1.0f);
            float ox1 = bx.x + off, oy1 = bx.y + off;
            float ox2 = bx.z + off, oy2 = bx.w + off;
            float car = (ox2 - ox1) * (oy2 - oy1);
            bool sup = false;
            if (lane < kept) {
                float lx = fmaxf(aX1, ox1), ly = fmaxf(aY1, oy1);
                float rx = fminf(aX2, ox2), ry = fminf(aY2, oy2);
                float w = fmaxf(rx - lx, 0.f), h = fmaxf(ry - ly, 0.f);
                float inter = w * h;
                float iou = inter / (aAR + car - inter);
                sup = iou > 0.6f;
            }
            if (lane + 64 < kept) {
                float lx = fmaxf(bX1, ox1), ly = fmaxf(bY1, oy1);
                float rx = fminf(bX2, ox2), ry = fminf(bY2, oy2);
                float w = fmaxf(rx - lx, 0.f), h = fmaxf(ry - ly, 0.f);
                float inter = w * h;
                float iou = inter / (bAR + car - inter);
                sup = sup || (iou > 0.6f);
            }
            unsigned long long m = __ballot(sup);
            if (m == 0ull) {        // kept
                if (kept < 64) {
                    if (lane == kept) { aX1 = ox1; aY1 = oy1; aX2 = ox2; aY2 = oy2; aAR = car; }
                } else {
                    if (lane == kept - 64) { bX1 = ox1; bY1 = oy1; bX2 = ox2; bY2 = oy2; bAR = car; }
                }
                if (lane == 0) { kb[kept] = bx; ks[kept] = sc; kl[kept] = lb; }
                kept++;
            } else if (ring < DETS) {   // suppressed: candidate for -1 padding
                if (lane == 0) { rb[ring] = bx; rl[ring] = lb; }
                ring++;
            }
        } else {                    // negative region (sorted: all the rest are too)
            if (ring < DETS) {
                if (lane == 0) { rb[ring] = bx; rl[ring] = lb; }
                ring++;
            }
            if (ring >= DETS) break;
        }
    }

    for (int k = lane; k < DETS; k += 64) {
        float4 bxo; float scv; int lv;
        if (k < kept) { bxo = kb[k]; scv = ks[k]; lv = kl[k]; }
        else { int q = k - kept; bxo = rb[q]; scv = -1.0f; lv = rl[q]; }
        float* ob = out + ((size_t)img * DETS + k) * 4;
        ob[0] = bxo.x; ob[1] = bxo.y; ob[2] = bxo.z; ob[3] = bxo.w;
        out[NIMG * DETS * 4 + img * DETS + k] = scv;
        out[NIMG * DETS * 5 + img * DETS + k] = (float)lv;
    }
}

// ---------------- launch ----------------

extern "C" void kernel_launch(void* const* d_in, const int* in_sizes, int n_in,
                              void* d_out, int out_size, void* d_ws, size_t ws_size,
                              hipStream_t stream) {
    (void)in_sizes; (void)n_in; (void)out_size; (void)ws_size;
    // setup_inputs() dict order: cls0, reg0, ctr0, anc0, cls1, reg1, ctr1, anc1, cls2, reg2, ctr2, anc2
    const float* cls0 = (const float*)d_in[0];
    const float* reg0 = (const float*)d_in[1];
    const float* ctr0 = (const float*)d_in[2];
    const float* anc0 = (const float*)d_in[3];
    const float* cls1 = (const float*)d_in[4];
    const float* reg1 = (const float*)d_in[5];
    const float* ctr1 = (const float*)d_in[6];
    const float* anc1 = (const float*)d_in[7];
    const float* cls2 = (const float*)d_in[8];
    const float* reg2 = (const float*)d_in[9];
    const float* ctr2 = (const float*)d_in[10];
    const float* anc2 = (const float*)d_in[11];
    float* out = (float*)d_out;
    char* ws = (char*)d_ws;

    // workspace layout (bytes)
    const size_t OFF_PARTS = 0;          // 24*16*4096*4 = 6,291,456 (fully overwritten; no memset)
    const size_t OFF_CNT   = 6291456;    // 24 counters, 64B apart = 1536
    const size_t ZERO_OFF  = 6291456;
    const size_t ZERO_B    = 1536;       // counters only
    const size_t OFF_VCUT  = 6292992;    // 24*4
    const size_t OFF_BUF   = 6293120;    // 24*2048*8  = 393,216
    const size_t OFF_CBOX  = 6686336;    // 8*3000*4*4 = 384,000 (16B aligned)
    const size_t OFF_CLAB  = 7070336;    // 8*3000*4   = 96,000
    const size_t OFF_GKEY  = 7166336;    // 8*3000*8   = 192,000 -> total 7,358,336

    unsigned int* parts = (unsigned int*)(ws + OFF_PARTS);
    unsigned int* cnt   = (unsigned int*)(ws + OFF_CNT);
    unsigned int* vcut  = (unsigned int*)(ws + OFF_VCUT);
    unsigned long long* buf  = (unsigned long long*)(ws + OFF_BUF);
    float* cand_box = (float*)(ws + OFF_CBOX);
    int*   cand_lab = (int*)(ws + OFF_CLAB);
    unsigned long long* gkey = (unsigned long long*)(ws + OFF_GKEY);

    hipMemsetAsync(ws + ZERO_OFF, 0, ZERO_B, stream);

    k_hist<<<dim3(NHBLK, NIMG, NLVL), 256, 0, stream>>>(cls0, cls1, cls2, ctr0, ctr1, ctr2, parts);
    k_find<<<24, 256, 0, stream>>>(parts, vcut);
    k_collect<<<dim3(NCBLK, NIMG, NLVL), 256, 0, stream>>>(cls0, cls1, cls2, ctr0, ctr1, ctr2,
                                                           vcut, cnt, buf);
    k_sort_pairs<<<24, 1024, 0, stream>>>(buf, cnt, reg0, reg1, reg2, anc0, anc1, anc2,
                                          cand_box, cand_lab, gkey);
    k_merge_nms<<<NIMG, 1024, 0, stream>>>(gkey, cand_box, cand_lab, out);
}

// Round 6
// 178.927 us; speedup vs baseline: 7.6895x; 1.1052x over previous
//
#include <hip/hip_runtime.h>

#define NCLS  80
#define TOPK  1000
#define NLVL  3
#define NIMG  8
#define NCAND 3000
#define DETS  100
#define CAP   2048          // cutoff-bin overshoot ~150-300 expected; 2048 = big margin
#define HBINS 4096          // q-space bins, 8192-ulp granules
#define NHBLK 16            // hist blocks per (img,level) pair
#define NCBLK 64            // collect blocks per (img,level) pair
#define GATH  512           // ranks pre-gathered to LDS in k_merge_nms
#define QBASE 0x3F800000u   // bits of q = 1.0 (q > 1 always)
#define QMAX  0x41C80000u   // bits of 25.0; q < 25  <=>  s > 0.2
#define IMGSZ 2048.0f

// ---------------- helpers ----------------

__device__ __forceinline__ float sigm(float x) {
    if (x >= 0.f) return 1.f / (1.f + expf(-x));
    float e = expf(x);
    return e / (1.f + e);
}

// q = (1+e^-a)(1+e^-b), rounding pinned (identical bits in k_hist and k_collect)
__device__ __forceinline__ unsigned int qbits(float ea, float t1) {
    return __float_as_uint(__fmul_rn(__fadd_rn(1.f, ea), t1));
}

// descending bitonic sort of N u64 keys in LDS (N power of 2, N >= blockDim)
__device__ __forceinline__ void bitonic_desc(unsigned long long* s, int N) {
    for (int k = 2; k <= N; k <<= 1) {
        for (int j = k >> 1; j > 0; j >>= 1) {
            __syncthreads();
            for (int i = threadIdx.x; i < N; i += blockDim.x) {
                int ixj = i ^ j;
                if (ixj > i) {
                    unsigned long long a = s[i], b = s[ixj];
                    bool up = ((i & k) == 0);
                    if (up ? (a < b) : (a > b)) { s[i] = b; s[ixj] = a; }
                }
            }
        }
    }
    __syncthreads();
}

__device__ __forceinline__ void lvl_select(int level,
    const float* c0, const float* c1, const float* c2,
    const float* t0, const float* t1, const float* t2,
    const float** cls, const float** ctr, int* hw) {
    if (level == 0)      { *cls = c0; *ctr = t0; *hw = 4096; }
    else if (level == 1) { *cls = c1; *ctr = t1; *hw = 1024; }
    else                 { *cls = c2; *ctr = t2; *hw = 256; }
}

// ---------------- stage 1: per-block partial histograms of q bits ----------------

__global__ void k_hist(const float* c0, const float* c1, const float* c2,
                       const float* t0, const float* t1, const float* t2,
                       unsigned int* parts) {
    int level = blockIdx.z, img = blockIdx.y;
    const float* cls; const float* ctr; int hw;
    lvl_select(level, c0, c1, c2, t0, t1, t2, &cls, &ctr, &hw);
    int n4 = hw * (NCLS / 4);          // float4 granules; 4 classes share one anchor
    const float4* cl4 = (const float4*)(cls + (size_t)img * hw * NCLS);
    const float* ct = ctr + (size_t)img * hw;
    __shared__ unsigned int h[HBINS];
    for (int i = threadIdx.x; i < HBINS; i += 256) h[i] = 0;
    __syncthreads();
    for (int i = blockIdx.x * 256 + threadIdx.x; i < n4; i += NHBLK * 256) {
        float4 v = cl4[i];
        int a = i / (NCLS / 4);        // 20 float4 per anchor row
        float eb = expf(-ct[a]);
        float t1 = __fadd_rn(1.f, eb);
        #pragma unroll
        for (int k = 0; k < 4; ++k) {
            float x = (k == 0) ? v.x : (k == 1) ? v.y : (k == 2) ? v.z : v.w;
            unsigned int qb = qbits(expf(-x), t1);
            if (qb < QMAX) {
                unsigned int bin = (qb - QBASE) >> 13;
                if (bin > HBINS - 1) bin = HBINS - 1;
                atomicAdd(&h[bin], 1u);
            }
        }
    }
    __syncthreads();
    unsigned int* P = parts + ((size_t)((img * NLVL + level) * NHBLK + blockIdx.x)) * HBINS;
    for (int i = threadIdx.x; i < HBINS; i += 256) P[i] = h[i];   // coalesced, no atomics
}

// ---------------- stage 2: merge partials + find cutoff V per (img,level) ----------------
// q ascending == score descending: scan from bin 0 upward.

__global__ void k_find(const unsigned int* parts, unsigned int* vcut) {
    int pair = blockIdx.x;
    int tid = threadIdx.x;      // 256 threads
    __shared__ unsigned int hb[HBINS];
    __shared__ unsigned int segsum[256];
    __shared__ unsigned int pref[256];
    unsigned int acc[HBINS / 256];
    #pragma unroll
    for (int j = 0; j < HBINS / 256; ++j) acc[j] = 0;
    for (int blk = 0; blk < NHBLK; ++blk) {
        const unsigned int* P = parts + ((size_t)(pair * NHBLK + blk)) * HBINS;
        #pragma unroll
        for (int j = 0; j < HBINS / 256; ++j) acc[j] += P[tid + 256 * j];
    }
    #pragma unroll
    for (int j = 0; j < HBINS / 256; ++j) hb[tid + 256 * j] = acc[j];
    __syncthreads();
    unsigned int seg = 0;
    #pragma unroll
    for (int j = 0; j < 16; ++j) seg += hb[16 * tid + j];   // thread owns bins [16t,16t+16)
    segsum[tid] = seg;
    pref[tid] = seg;
    __syncthreads();
    for (int off = 1; off < 256; off <<= 1) {
        unsigned int v = (tid >= off) ? pref[tid - off] : 0u;
        __syncthreads();
        pref[tid] += v;
        __syncthreads();
    }
    unsigned int incl = pref[tid];
    unsigned int excl = incl - seg;
    if (excl < (unsigned int)TOPK && incl >= (unsigned int)TOPK) {
        unsigned int cum = excl; int B = HBINS - 1;
        for (int b = 16 * tid; b < 16 * tid + 16; ++b) {
            cum += hb[b];
            if (cum >= (unsigned int)TOPK) { B = b; break; }
        }
        vcut[pair] = (B >= HBINS - 1) ? QMAX : (QBASE + ((unsigned int)(B + 1) << 13));
    }
    if (tid == 255 && pref[255] < (unsigned int)TOPK)
        vcut[pair] = QMAX;   // fewer than TOPK pass threshold: collect all passing
}

// ---------------- stage 3: collect candidates with q_bits < V ----------------
// Survivors staged in LDS (fast local atomics); ONE global atomic per block
// (round-4 postmortem: 36k same-cacheline device atomics serialized ~85 us).
// Slot order within buf is irrelevant: k_sort_pairs sorts by the full key.

__global__ void k_collect(const float* c0, const float* c1, const float* c2,
                          const float* t0, const float* t1, const float* t2,
                          const unsigned int* vcut, unsigned int* counters,
                          unsigned long long* buf) {
    int level = blockIdx.z, img = blockIdx.y;
    const float* cls; const float* ctr; int hw;
    lvl_select(level, c0, c1, c2, t0, t1, t2, &cls, &ctr, &hw);
    int n4 = hw * (NCLS / 4);
    int pair = img * NLVL + level;
    const float4* cl4 = (const float4*)(cls + (size_t)img * hw * NCLS);
    const float* ct = ctr + (size_t)img * hw;
    unsigned int V = vcut[pair];
    __shared__ unsigned long long sbuf[2048];
    __shared__ unsigned int scnt;
    __shared__ unsigned int sbase;
    if (threadIdx.x == 0) scnt = 0;
    __syncthreads();
    for (int i = blockIdx.x * 256 + threadIdx.x; i < n4; i += NCBLK * 256) {
        float4 v = cl4[i];
        int a = i / (NCLS / 4);
        float cta = ct[a];
        float eb = expf(-cta);
        float t1 = __fadd_rn(1.f, eb);
        #pragma unroll
        for (int k = 0; k < 4; ++k) {
            float x = (k == 0) ? v.x : (k == 1) ? v.y : (k == 2) ? v.z : v.w;
            unsigned int qb = qbits(expf(-x), t1);
            if (qb < V) {
                // exact score, bit-identical to rounds 1-5 (validated absmax 0.0)
                float s = sqrtf(sigm(x) * sigm(cta));
                unsigned int e = (unsigned int)(4 * i + k);
                unsigned int slot = atomicAdd(&scnt, 1u);   // LDS atomic, sparse
                if (slot < 2048)
                    sbuf[slot] = ((unsigned long long)__float_as_uint(s) << 32) | (~e);
            }
        }
    }
    __syncthreads();
    unsigned int cl_n = scnt; if (cl_n > 2048) cl_n = 2048;
    if (threadIdx.x == 0)
        sbase = atomicAdd(&counters[pair * 16], cl_n);      // one global atomic/block
    __syncthreads();
    unsigned int base = sbase;
    for (unsigned int idx = threadIdx.x; idx < cl_n; idx += 256) {
        unsigned int g = base + idx;
        if (g < CAP) buf[(size_t)pair * CAP + g] = sbuf[idx];   // coalesced flush
    }
}

// ---------------- stage 4: per-(img,level) sort -> top-1000, decode boxes ----------------

__global__ void __launch_bounds__(1024)
k_sort_pairs(const unsigned long long* buf, const unsigned int* counters,
             const float* r0, const float* r1, const float* r2,
             const float* a0, const float* a1, const float* a2,
             float* cand_box, int* cand_lab, unsigned long long* gkey) {
    int pair = blockIdx.x;
    int img = pair / NLVL, level = pair % NLVL;
    __shared__ unsigned long long s[CAP];
    int cnt = (int)counters[pair * 16]; if (cnt > CAP) cnt = CAP;
    for (int i = threadIdx.x; i < CAP; i += blockDim.x)
        s[i] = (i < cnt) ? buf[(size_t)pair * CAP + i] : 0ull;
    bitonic_desc(s, CAP);   // leading __syncthreads inside covers the load
    const float* reg; const float* anc; int hw;
    if (level == 0)      { reg = r0; anc = a0; hw = 4096; }
    else if (level == 1) { reg = r1; anc = a1; hw = 1024; }
    else                 { reg = r2; anc = a2; hw = 256; }
    const float* rg = reg + (size_t)img * hw * 4;
    for (int r = threadIdx.x; r < TOPK; r += blockDim.x) {
        unsigned long long key = s[r];
        int cpos = level * TOPK + r;
        size_t o = (size_t)img * NCAND + cpos;
        float b0 = 0, b1 = 0, b2 = 0, b3 = 0; int lab = 0; unsigned int bits = 0;
        if (key != 0ull) {
            bits = (unsigned int)(key >> 32);
            unsigned int idx = ~((unsigned int)key);
            int a = (int)(idx / NCLS); lab = (int)(idx % NCLS);
            float ax1 = anc[a * 4 + 0], ay1 = anc[a * 4 + 1];
            float ax2 = anc[a * 4 + 2], ay2 = anc[a * 4 + 3];
            float cx = 0.5f * (ax1 + ax2), cy = 0.5f * (ay1 + ay2);
            float w = ax2 - ax1, h = ay2 - ay1;
            float e0 = rg[a * 4 + 0] * w, e1 = rg[a * 4 + 1] * h;
            float e2 = rg[a * 4 + 2] * w, e3 = rg[a * 4 + 3] * h;
            b0 = fminf(fmaxf(cx - e0, 0.f), IMGSZ);
            b1 = fminf(fmaxf(cy - e1, 0.f), IMGSZ);
            b2 = fminf(fmaxf(cx + e2, 0.f), IMGSZ);
            b3 = fminf(fmaxf(cy + e3, 0.f), IMGSZ);
        }
        cand_box[o * 4 + 0] = b0; cand_box[o * 4 + 1] = b1;
        cand_box[o * 4 + 2] = b2; cand_box[o * 4 + 3] = b3;
        cand_lab[o] = lab;
        // global key: ties in bits break by smaller concat position (matches top_k)
        gkey[o] = ((unsigned long long)bits << 32) | (unsigned int)(~((unsigned int)cpos));
    }
}

// ---------------- stage 5 (fused): 3-way merge + BATCHED greedy NMS + output ----------------
//
// Output = first 100 kept candidates in global rank order. Round-5 postmortem:
// the rank-at-a-time serial scan was ~570 cyc/iter of loop-carried stall.
// Now: 64 ranks per wave step — (1) lanes check IoU vs kept list in parallel,
// (2) intra-batch column masks from an LDS staging array, (3) wave-uniform
// greedy resolve via ctz + one ballot per kept box. Exactly equivalent to
// sequential greedy, including the kept==100 early-stop rank boundary.

__global__ void __launch_bounds__(1024)
k_merge_nms(const unsigned long long* gkey, const float* cand_box, const int* cand_lab,
            float* out) {
    int img = blockIdx.x;
    int tid = threadIdx.x;
    __shared__ unsigned long long A[TOPK], B[TOPK], C[TOPK];
    __shared__ unsigned long long M[2 * TOPK];
    __shared__ unsigned long long S[NCAND];
    __shared__ float4 wbox[GATH];
    __shared__ int    wlab[GATH];
    __shared__ float4 sbx[64]; __shared__ float sar[64];
    __shared__ float4 koff[DETS]; __shared__ float karr[DETS];
    __shared__ float4 kb[DETS]; __shared__ float ks[DETS]; __shared__ int kl[DETS];
    __shared__ float4 rb[DETS]; __shared__ int rl[DETS];

    const unsigned long long* G = gkey + (size_t)img * NCAND;
    for (int i = tid; i < TOPK; i += 1024) { A[i] = G[i]; B[i] = G[TOPK + i]; C[i] = G[2 * TOPK + i]; }
    __syncthreads();

    // merge-path A (1000) + B (1000) -> M (2000), descending, keys unique
    for (int k = tid; k < 2 * TOPK; k += 1024) {
        int lo = max(0, k - TOPK), hi = min(k, TOPK);
        while (lo < hi) {
            int mid = (lo + hi) >> 1;
            if (A[mid] > B[k - mid - 1]) lo = mid + 1; else hi = mid;
        }
        int i = lo, j = k - lo;
        unsigned long long av = (i < TOPK) ? A[i] : 0ull;
        unsigned long long bv = (j < TOPK) ? B[j] : 0ull;
        M[k] = (av > bv) ? av : bv;
    }
    __syncthreads();
    // merge-path M (2000) + C (1000) -> S (3000)
    for (int k = tid; k < NCAND; k += 1024) {
        int lo = max(0, k - TOPK), hi = min(k, 2 * TOPK);
        while (lo < hi) {
            int mid = (lo + hi) >> 1;
            if (M[mid] > C[k - mid - 1]) lo = mid + 1; else hi = mid;
        }
        int i = lo, j = k - lo;
        unsigned long long mv = (i < 2 * TOPK) ? M[i] : 0ull;
        unsigned long long cv = (j < TOPK) ? C[j] : 0ull;
        S[k] = (mv > cv) ? mv : cv;
    }
    __syncthreads();

    // gather candidate data for the first GATH ranks into LDS (guard zero keys)
    const float4* CB4 = (const float4*)cand_box + (size_t)img * NCAND;
    const int* CL = cand_lab + (size_t)img * NCAND;
    if (tid < GATH) {
        unsigned int pos = ~((unsigned int)S[tid]);
        float4 b4 = make_float4(0.f, 0.f, 0.f, 0.f); int lbv = 0;
        if (pos < NCAND) { b4 = CB4[pos]; lbv = CL[pos]; }
        wbox[tid] = b4; wlab[tid] = lbv;
    }
    __syncthreads();

    if (tid >= 64) return;   // single wave finishes (batched, short)
    int lane = tid;
    unsigned long long lmask_lt = (lane == 0) ? 0ull : (~0ull >> (64 - lane));

    int kept = 0, ring = 0, r = 0;

    while (kept < DETS && r < NCAND) {
        int rank = r + lane;
        unsigned long long key = (rank < NCAND) ? S[rank] : 0ull;
        unsigned int bits = (unsigned int)(key >> 32);
        unsigned long long pm = __ballot(bits != 0u);   // positives form a prefix (sorted)
        int npos = (pm == ~0ull) ? 64 : (int)__builtin_ctzll(~pm);
        if (npos == 0) break;                           // negatives from rank r onward

        float4 bx = make_float4(0.f, 0.f, 0.f, 0.f); int lb = 0;
        if (lane < npos) {
            unsigned int pos = ~((unsigned int)key);
            if (rank < GATH) { bx = wbox[rank]; lb = wlab[rank]; }
            else if (pos < NCAND) { bx = CB4[pos]; lb = CL[pos]; }
        }
        float off = (float)lb * (IMGSZ + 1.0f);
        float ox1 = bx.x + off, oy1 = bx.y + off;
        float ox2 = bx.z + off, oy2 = bx.w + off;
        float car = (ox2 - ox1) * (oy2 - oy1);
        sbx[lane] = make_float4(ox1, oy1, ox2, oy2);
        sar[lane] = car;        // single wave: program-order LDS, no barrier needed

        // (1) vs previously-kept boxes (broadcast reads, parallel across lanes)
        bool supk = false;
        for (int k2 = 0; k2 < kept; ++k2) {
            float4 kk = koff[k2]; float ka = karr[k2];
            float lx = fmaxf(kk.x, ox1), ly = fmaxf(kk.y, oy1);
            float rx = fminf(kk.z, ox2), ry = fminf(kk.w, oy2);
            float w = fmaxf(rx - lx, 0.f), h = fmaxf(ry - ly, 0.f);
            float inter = w * h;
            supk = supk || (inter / (ka + car - inter) > 0.6f);
        }
        // (2) intra-batch column mask: who among earlier slots suppresses me
        unsigned long long col = 0ull;
        for (int i = 0; i < npos; ++i) {
            float4 c = sbx[i]; float ca = sar[i];
            float lx = fmaxf(c.x, ox1), ly = fmaxf(c.y, oy1);
            float rx = fminf(c.z, ox2), ry = fminf(c.w, oy2);
            float w = fmaxf(rx - lx, 0.f), h = fmaxf(ry - ly, 0.f);
            float inter = w * h;
            if ((inter / (ca + car - inter) > 0.6f) && (i < lane)) col |= (1ull << i);
        }
        // (3) wave-uniform greedy resolve (picks are in increasing slot order)
        unsigned long long undecided = __ballot((lane < npos) && !supk);
        unsigned long long aliveSel = 0ull;
        int capleft = DETS - kept;
        int lastSlot = npos - 1;
        while (undecided) {
            int i = (int)__builtin_ctzll(undecided);
            aliveSel |= (1ull << i);
            undecided &= ~(1ull << i);
            if (--capleft == 0) { lastSlot = i; break; }   // kept hits 100 at slot i
            unsigned long long row = __ballot(((col >> i) & 1ull) != 0ull);
            undecided &= ~row;
        }
        unsigned long long region = (lastSlot >= 63) ? ~0ull : ((1ull << (lastSlot + 1)) - 1ull);
        region &= (npos >= 64) ? ~0ull : ((1ull << npos) - 1ull);
        unsigned long long rejm = region & ~aliveSel;

        if ((aliveSel >> lane) & 1ull) {
            int ki = kept + (int)__popcll(aliveSel & lmask_lt);
            koff[ki] = make_float4(ox1, oy1, ox2, oy2); karr[ki] = car;
            kb[ki] = bx; ks[ki] = __uint_as_float(bits); kl[ki] = lb;
        }
        if ((rejm >> lane) & 1ull) {
            int ri = ring + (int)__popcll(rejm & lmask_lt);
            if (ri < DETS) { rb[ri] = bx; rl[ri] = lb; }
        }
        kept += (int)__popcll(aliveSel);
        ring += (int)__popcll(rejm);
        r += lastSlot + 1;
    }

    // negative / padding fill: remaining ranks in order until ring >= DETS
    while (kept < DETS && ring < DETS && r < NCAND) {
        int rank = r + lane;
        if (rank < NCAND) {
            int ri = ring + lane;
            if (ri < DETS) {
                unsigned long long key = S[rank];
                unsigned int pos = ~((unsigned int)key);
                float4 bx = make_float4(0.f, 0.f, 0.f, 0.f); int lb = 0;
                if (rank < GATH) { bx = wbox[rank]; lb = wlab[rank]; }
                else if (pos < NCAND) { bx = CB4[pos]; lb = CL[pos]; }
                rb[ri] = bx; rl[ri] = lb;
            }
        }
        int take = NCAND - r; if (take > 64) take = 64;
        ring += take;
        r += 64;
    }

    for (int k = lane; k < DETS; k += 64) {
        float4 bxo; float scv; int lv;
        if (k < kept) { bxo = kb[k]; scv = ks[k]; lv = kl[k]; }
        else { int q = k - kept; bxo = rb[q]; scv = -1.0f; lv = rl[q]; }
        float* ob = out + ((size_t)img * DETS + k) * 4;
        ob[0] = bxo.x; ob[1] = bxo.y; ob[2] = bxo.z; ob[3] = bxo.w;
        out[NIMG * DETS * 4 + img * DETS + k] = scv;
        out[NIMG * DETS * 5 + img * DETS + k] = (float)lv;
    }
}

// ---------------- launch ----------------

extern "C" void kernel_launch(void* const* d_in, const int* in_sizes, int n_in,
                              void* d_out, int out_size, void* d_ws, size_t ws_size,
                              hipStream_t stream) {
    (void)in_sizes; (void)n_in; (void)out_size; (void)ws_size;
    // setup_inputs() dict order: cls0, reg0, ctr0, anc0, cls1, reg1, ctr1, anc1, cls2, reg2, ctr2, anc2
    const float* cls0 = (const float*)d_in[0];
    const float* reg0 = (const float*)d_in[1];
    const float* ctr0 = (const float*)d_in[2];
    const float* anc0 = (const float*)d_in[3];
    const float* cls1 = (const float*)d_in[4];
    const float* reg1 = (const float*)d_in[5];
    const float* ctr1 = (const float*)d_in[6];
    const float* anc1 = (const float*)d_in[7];
    const float* cls2 = (const float*)d_in[8];
    const float* reg2 = (const float*)d_in[9];
    const float* ctr2 = (const float*)d_in[10];
    const float* anc2 = (const float*)d_in[11];
    float* out = (float*)d_out;
    char* ws = (char*)d_ws;

    // workspace layout (bytes)
    const size_t OFF_PARTS = 0;          // 24*16*4096*4 = 6,291,456 (fully overwritten; no memset)
    const size_t OFF_CNT   = 6291456;    // 24 counters, 64B apart = 1536
    const size_t ZERO_OFF  = 6291456;
    const size_t ZERO_B    = 1536;       // counters only
    const size_t OFF_VCUT  = 6292992;    // 24*4
    const size_t OFF_BUF   = 6293120;    // 24*2048*8  = 393,216
    const size_t OFF_CBOX  = 6686336;    // 8*3000*4*4 = 384,000 (16B aligned)
    const size_t OFF_CLAB  = 7070336;    // 8*3000*4   = 96,000
    const size_t OFF_GKEY  = 7166336;    // 8*3000*8   = 192,000 -> total 7,358,336

    unsigned int* parts = (unsigned int*)(ws + OFF_PARTS);
    unsigned int* cnt   = (unsigned int*)(ws + OFF_CNT);
    unsigned int* vcut  = (unsigned int*)(ws + OFF_VCUT);
    unsigned long long* buf  = (unsigned long long*)(ws + OFF_BUF);
    float* cand_box = (float*)(ws + OFF_CBOX);
    int*   cand_lab = (int*)(ws + OFF_CLAB);
    unsigned long long* gkey = (unsigned long long*)(ws + OFF_GKEY);

    hipMemsetAsync(ws + ZERO_OFF, 0, ZERO_B, stream);

    k_hist<<<dim3(NHBLK, NIMG, NLVL), 256, 0, stream>>>(cls0, cls1, cls2, ctr0, ctr1, ctr2, parts);
    k_find<<<24, 256, 0, stream>>>(parts, vcut);
    k_collect<<<dim3(NCBLK, NIMG, NLVL), 256, 0, stream>>>(cls0, cls1, cls2, ctr0, ctr1, ctr2,
                                                           vcut, cnt, buf);
    k_sort_pairs<<<24, 1024, 0, stream>>>(buf, cnt, reg0, reg1, reg2, anc0, anc1, anc2,
                                          cand_box, cand_lab, gkey);
    k_merge_nms<<<NIMG, 1024, 0, stream>>>(gkey, cand_box, cand_lab, out);
}